// Round 5
// baseline (906.502 us; speedup 1.0000x reference)
//
#include <hip/hip_runtime.h>
#include <math.h>

#define TOK 9232      // B*N = 16*577
#define EMB 1024
#define NQKV 3072
#define FFD 4096
#define NSEQ 577
#define KQKV 1088     // 1024 + 64 LoRA rank-cols
#define KFC2 4352     // 4096 + 256 adapter cols

typedef __bf16 bf16x8 __attribute__((ext_vector_type(8)));
typedef float f32x4 __attribute__((ext_vector_type(4)));
typedef unsigned short ushort8 __attribute__((ext_vector_type(8)));
typedef unsigned short ushort4v __attribute__((ext_vector_type(4)));

typedef __attribute__((address_space(3))) unsigned int lds_u32_t;
typedef const __attribute__((address_space(1))) unsigned int glob_u32_t;

__device__ __forceinline__ void async16(void* lds, const void* g) {
    __builtin_amdgcn_global_load_lds((glob_u32_t*)g, (lds_u32_t*)lds, 16, 0, 0);
}

__device__ __forceinline__ unsigned short f2bf(float f) {
    unsigned int u = __builtin_bit_cast(unsigned int, f);
    u = (u + 0x7fffu + ((u >> 16) & 1u)) >> 16;
    return (unsigned short)u;
}
__device__ __forceinline__ float bf2f(unsigned short s) {
    unsigned int u = ((unsigned int)s) << 16;
    return __builtin_bit_cast(float, u);
}
__device__ __forceinline__ float gelu_exact(float x) {
    return 0.5f * x * (1.0f + erff(x * 0.70710678118654752f));
}

// ---------- weight conversion / packing ----------
// generic: src row-major [*][K] f32 -> dst [*][LD] bf16 (cols 0..K-1)
__global__ void k_pack_str(const float* __restrict__ src, unsigned short* __restrict__ dst,
                           int K, int LD, int tot) {
    int i = blockIdx.x * 256 + threadIdx.x;
    if (i >= tot) return;
    int o = i / K, k = i - o * K;
    dst[(size_t)o * LD + k] = f2bf(src[i]);
}
// lora_B [4][3072][16] -> w_qkvcat[o][1024 + x*16 + r]
__global__ void k_pack_bcat(const float* __restrict__ Bw, unsigned short* __restrict__ out) {
    int i = blockIdx.x * 256 + threadIdx.x;
    if (i >= 3072 * 64) return;
    int o = i >> 6, j = i & 63, x = j >> 4, r = j & 15;
    out[(size_t)o * KQKV + 1024 + j] = f2bf(Bw[x * 3072 * 16 + o * 16 + r]);
}
// ad_up_w [4][1024][64] -> w_fc2cat[o][4096 + x*64 + h]
__global__ void k_pack_u(const float* __restrict__ Uw, unsigned short* __restrict__ out) {
    int i = blockIdx.x * 256 + threadIdx.x;
    if (i >= 1024 * 256) return;
    int o = i >> 8, j = i & 255, x = j >> 6, h = j & 63;
    out[(size_t)o * KFC2 + 4096 + j] = f2bf(Uw[x * 65536 + o * 64 + h]);
}

// ---------- fused layernorm + 4-expert gate softmax, one block per token ----------
__global__ __launch_bounds__(256) void k_ln_gates(const float* __restrict__ x,
                                                  const float* __restrict__ g,
                                                  const float* __restrict__ b,
                                                  const float* __restrict__ gw,
                                                  unsigned short* __restrict__ out, int ostride,
                                                  float* __restrict__ gates) {
    int t = blockIdx.x;
    int tid = threadIdx.x;
    const float* xp = x + (size_t)t * EMB;
    float4 v = ((const float4*)xp)[tid];
    float s = v.x + v.y + v.z + v.w;
    float sq = v.x * v.x + v.y * v.y + v.z * v.z + v.w * v.w;
    #pragma unroll
    for (int off = 32; off > 0; off >>= 1) {
        s += __shfl_down(s, off);
        sq += __shfl_down(sq, off);
    }
    __shared__ float red[8];
    if ((tid & 63) == 0) { red[tid >> 6] = s; red[(tid >> 6) + 4] = sq; }
    __syncthreads();
    float S = red[0] + red[1] + red[2] + red[3];
    float SQ = red[4] + red[5] + red[6] + red[7];
    float mean = S * (1.0f / EMB);
    float var = SQ * (1.0f / EMB) - mean * mean;
    float rstd = rsqrtf(var + 1e-6f);
    float4 gv = ((const float4*)g)[tid];
    float4 bv = ((const float4*)b)[tid];
    float n0 = (v.x - mean) * rstd * gv.x + bv.x;
    float n1 = (v.y - mean) * rstd * gv.y + bv.y;
    float n2 = (v.z - mean) * rstd * gv.z + bv.z;
    float n3 = (v.w - mean) * rstd * gv.w + bv.w;
    ushort4v o;
    o[0] = f2bf(n0); o[1] = f2bf(n1); o[2] = f2bf(n2); o[3] = f2bf(n3);
    *(ushort4v*)(out + (size_t)t * ostride + tid * 4) = o;
    float p[4];
    #pragma unroll
    for (int xx = 0; xx < 4; ++xx) {
        float4 gr = ((const float4*)(gw + xx * EMB))[tid];
        p[xx] = n0 * gr.x + n1 * gr.y + n2 * gr.z + n3 * gr.w;
    }
    #pragma unroll
    for (int off = 32; off > 0; off >>= 1) {
        #pragma unroll
        for (int xx = 0; xx < 4; ++xx) p[xx] += __shfl_down(p[xx], off);
    }
    __shared__ float red2[4][4];
    if ((tid & 63) == 0) {
        #pragma unroll
        for (int xx = 0; xx < 4; ++xx) red2[tid >> 6][xx] = p[xx];
    }
    __syncthreads();
    if (tid == 0) {
        float l[4];
        #pragma unroll
        for (int xx = 0; xx < 4; ++xx) l[xx] = red2[0][xx] + red2[1][xx] + red2[2][xx] + red2[3][xx];
        float m = fmaxf(fmaxf(l[0], l[1]), fmaxf(l[2], l[3]));
        float e[4], ssum = 0.f;
        #pragma unroll
        for (int xx = 0; xx < 4; ++xx) { e[xx] = expf(l[xx] - m); ssum += e[xx]; }
        float inv = 1.0f / ssum;
        #pragma unroll
        for (int xx = 0; xx < 4; ++xx) gates[t * 4 + xx] = e[xx] * inv;
    }
}

// normedcat[t][1024+j] = gates[t][j>>4] * lora_h[t][j], j<64
__global__ void k_make_hw(const float* __restrict__ gates, const float* __restrict__ lh,
                          unsigned short* __restrict__ ncat) {
    int i = blockIdx.x * 256 + threadIdx.x;
    if (i >= TOK * 64) return;
    int t = i >> 6, j = i & 63;
    ncat[(size_t)t * KQKV + 1024 + j] = f2bf(gates[t * 4 + (j >> 4)] * lh[i]);
}

// h1cat[t][4096+j] = ag[t][j>>6] * gelu(ahpre[t][j]), j<256
__global__ void k_make_ahw(const float* __restrict__ ag, const float* __restrict__ ahpre,
                           unsigned short* __restrict__ h1cat) {
    int i = blockIdx.x * 256 + threadIdx.x;
    if (i >= TOK * 256) return;
    int t = i >> 8, j = i & 255;
    h1cat[(size_t)t * KFC2 + 4096 + j] = f2bf(ag[t * 4 + (j >> 6)] * gelu_exact(ahpre[i]));
}

// tok2[t][o] += sum_x ag[t][x] * ad_up_b[x][o]
__global__ __launch_bounds__(256) void k_adbias(const float* __restrict__ ag,
                                                const float* __restrict__ upb,
                                                float* __restrict__ tok2) {
    int t = blockIdx.x;
    int tid = threadIdx.x;
    float g0 = ag[t * 4 + 0], g1 = ag[t * 4 + 1], g2 = ag[t * 4 + 2], g3 = ag[t * 4 + 3];
    float4 b0 = ((const float4*)(upb + 0 * EMB))[tid];
    float4 b1 = ((const float4*)(upb + 1 * EMB))[tid];
    float4 b2 = ((const float4*)(upb + 2 * EMB))[tid];
    float4 b3 = ((const float4*)(upb + 3 * EMB))[tid];
    float4 r = ((float4*)(tok2 + (size_t)t * EMB))[tid];
    r.x += g0 * b0.x + g1 * b1.x + g2 * b2.x + g3 * b3.x;
    r.y += g0 * b0.y + g1 * b1.y + g2 * b2.y + g3 * b3.y;
    r.z += g0 * b0.z + g1 * b1.z + g2 * b2.z + g3 * b3.z;
    r.w += g0 * b0.w + g1 * b1.w + g2 * b2.w + g3 * b3.w;
    ((float4*)(tok2 + (size_t)t * EMB))[tid] = r;
}

// ========== 256x256 GEMM, BK=32, 3-buffer LDS ring, counted vmcnt(8) ==========
// C[M,N] = A[M,K]@W[N,K]^T (+bias)(gelu?)(+resid). 512 thr = 8 waves (2M x 4N).
// LDS 96KB: SA/SB[3][256][32]. Swizzle: byte ^= ((row>>1)&3)<<4 (involution).
#define VMCNT8 asm volatile("s_waitcnt vmcnt(8)" ::: "memory")
#define BAR __builtin_amdgcn_s_barrier()

template<bool GELU, bool BF16OUT>
__global__ __launch_bounds__(512, 2) void k_gemm256(
    const unsigned short* __restrict__ A, const unsigned short* __restrict__ W,
    int M, int N, int K,
    const float* __restrict__ bias, const float* __restrict__ resid,
    void* __restrict__ Cout, int ldc, int NT)
{
    __shared__ unsigned short SA[3][256][32];
    __shared__ unsigned short SB[3][256][32];

    int tid = threadIdx.x;
    int l = tid & 63, w = tid >> 6;
    int wm = w >> 2, wn = w & 3;
    int lr = l & 15, lk8 = (l >> 4) * 8;

    // T1: bijective XCD remap, m-major flattening
    int nwg = gridDim.x, orig = blockIdx.x;
    int xcd = orig & 7, lid = orig >> 3;
    int q = nwg >> 3, r = nwg & 7;
    int wg = (xcd < r ? xcd * (q + 1) : r * (q + 1) + (xcd - r) * q) + lid;
    int bm = (wg / NT) * 256;
    int bn = (wg % NT) * 256;

    int KT = K >> 5;

    // per-thread staging source pointers (row clamped, slot inverse-swizzled)
    const unsigned short *srcA0, *srcA1, *srcB0, *srcB1;
    {
        int P0 = w * 1024 + l * 16;
        int row0 = P0 >> 6, slot0 = ((P0 >> 4) & 3) ^ ((row0 >> 1) & 3);
        int row1 = row0 + 128, slot1 = ((P0 >> 4) & 3) ^ ((row1 >> 1) & 3);
        int ra0 = bm + row0; if (ra0 > M - 1) ra0 = M - 1;
        int ra1 = bm + row1; if (ra1 > M - 1) ra1 = M - 1;
        int rb0 = bn + row0; if (rb0 > N - 1) rb0 = N - 1;
        int rb1 = bn + row1; if (rb1 > N - 1) rb1 = N - 1;
        srcA0 = A + (size_t)ra0 * K + slot0 * 8;
        srcA1 = A + (size_t)ra1 * K + slot1 * 8;
        srcB0 = W + (size_t)rb0 * K + slot0 * 8;
        srcB1 = W + (size_t)rb1 * K + slot1 * 8;
    }

    f32x4 acc[8][4];
    #pragma unroll
    for (int i = 0; i < 8; ++i)
        #pragma unroll
        for (int j = 0; j < 4; ++j) acc[i][j] = (f32x4){0.f, 0.f, 0.f, 0.f};

#define STAGE(s_, sb_) do {                                      \
    unsigned short* da_ = &SA[sb_][0][0] + (w << 9);             \
    unsigned short* db_ = &SB[sb_][0][0] + (w << 9);             \
    int ko_ = (s_) << 5;                                         \
    async16(da_,        srcA0 + ko_);                            \
    async16(da_ + 4096, srcA1 + ko_);                            \
    async16(db_,        srcB0 + ko_);                            \
    async16(db_ + 4096, srcB1 + ko_);                            \
} while (0)

    // prologue: tiles 0,1 into bufs 0,1 (no wait; loop's vmcnt covers)
    STAGE(0, 0);
    STAGE(1, 1);

    int cb = 0, sb = 2;
    #pragma unroll 1
    for (int t = 0; t < KT; ++t) {
        int s = t + 2; if (s >= KT) s -= KT;   // wrap re-stage is harmless (never read)
        STAGE(s, sb);
        VMCNT8;    // tiles t+1 (4) + t+2 (4) may remain in flight; tile t drained
        BAR;
        bf16x8 a[8], b[4];
        const char* baseA = (const char*)&SA[cb][0][0];
        const char* baseB = (const char*)&SB[cb][0][0];
        #pragma unroll
        for (int f = 0; f < 8; ++f) {
            int rw = wm * 128 + f * 16 + lr;
            int byte = (rw << 6) + ((lk8 << 1) ^ (((rw >> 1) & 3) << 4));
            a[f] = *(const bf16x8*)(baseA + byte);
        }
        #pragma unroll
        for (int n = 0; n < 4; ++n) {
            int rw = wn * 64 + n * 16 + lr;
            int byte = (rw << 6) + ((lk8 << 1) ^ (((rw >> 1) & 3) << 4));
            b[n] = *(const bf16x8*)(baseB + byte);
        }
        __builtin_amdgcn_s_setprio(1);
        #pragma unroll
        for (int f = 0; f < 8; ++f)
            #pragma unroll
            for (int n = 0; n < 4; ++n)
                acc[f][n] = __builtin_amdgcn_mfma_f32_16x16x32_bf16(a[f], b[n], acc[f][n], 0, 0, 0);
        __builtin_amdgcn_s_setprio(0);
        BAR;       // reads of buf cb done before iteration t+1 re-stages slot cb
        cb = (cb == 2) ? 0 : cb + 1;
        sb = (sb == 2) ? 0 : sb + 1;
    }
#undef STAGE

    // epilogue (scalar stores; diagnostic for write-allocate theory)
    #pragma unroll
    for (int n = 0; n < 4; ++n) {
        int col = bn + wn * 64 + n * 16 + lr;
        float bv = bias ? bias[col] : 0.0f;
        #pragma unroll
        for (int f = 0; f < 8; ++f) {
            int row0 = bm + wm * 128 + f * 16 + (l >> 4) * 4;
            #pragma unroll
            for (int rr = 0; rr < 4; ++rr) {
                int row = row0 + rr;
                if (row < M) {
                    float c = acc[f][n][rr] + bv;
                    if (GELU) c = gelu_exact(c);
                    if (resid) c += resid[(size_t)row * ldc + col];
                    if (BF16OUT) ((unsigned short*)Cout)[(size_t)row * ldc + col] = f2bf(c);
                    else ((float*)Cout)[(size_t)row * ldc + col] = c;
                }
            }
        }
    }
}

// ---------- small-N MFMA GEMM (128x128 tile, m97 structure) ----------
template<bool BF16OUT>
__global__ __launch_bounds__(256) void k_gemm128(
    const unsigned short* __restrict__ A, int lda,
    const unsigned short* __restrict__ W,
    int M, int N, int K,
    const float* __restrict__ bias,
    void* __restrict__ Cout, int ldc, int gy)
{
    __shared__ unsigned short As[128][32];
    __shared__ unsigned short Ws[128][32];
    int tid = threadIdx.x;
    int nwg = gridDim.x, orig = blockIdx.x;
    int xcd = orig & 7, lid = orig >> 3;
    int q = nwg >> 3, r = nwg & 7;
    int wg = (xcd < r ? xcd * (q + 1) : r * (q + 1) + (xcd - r) * q) + lid;
    int bm128 = (wg / gy) * 128;
    int bn128 = (wg % gy) * 128;

    int l = tid & 63, w = tid >> 6;
    int wr = w >> 1, wc = w & 1;
    int lr = l & 15, lk = (l >> 4) * 8;
    int srow = l >> 2;
    int sslot = (l & 3) * 8;

    f32x4 acc[4][4];
    #pragma unroll
    for (int m = 0; m < 4; ++m)
        #pragma unroll
        for (int n = 0; n < 4; ++n) acc[m][n] = (f32x4){0.f, 0.f, 0.f, 0.f};

    for (int k0 = 0; k0 < K; k0 += 32) {
        #pragma unroll
        for (int i = 0; i < 2; ++i) {
            int row = w * 32 + i * 16 + srow;
            int ra = bm128 + row; if (ra >= M) ra = M - 1;
            async16((char*)&As[0][0] + w * 2048 + i * 1024,
                    A + (size_t)ra * lda + k0 + sslot);
            int rb = bn128 + row; if (rb >= N) rb = N - 1;
            async16((char*)&Ws[0][0] + w * 2048 + i * 1024,
                    W + (size_t)rb * K + k0 + sslot);
        }
        __syncthreads();
        bf16x8 af[4], bfr[4];
        #pragma unroll
        for (int m = 0; m < 4; ++m) af[m] = *(const bf16x8*)&As[wr * 64 + m * 16 + lr][lk];
        #pragma unroll
        for (int n = 0; n < 4; ++n) bfr[n] = *(const bf16x8*)&Ws[wc * 64 + n * 16 + lr][lk];
        #pragma unroll
        for (int m = 0; m < 4; ++m)
            #pragma unroll
            for (int n = 0; n < 4; ++n)
                acc[m][n] = __builtin_amdgcn_mfma_f32_16x16x32_bf16(af[m], bfr[n], acc[m][n], 0, 0, 0);
        __syncthreads();
    }

    int rb0 = bm128 + wr * 64;
    int cb0 = bn128 + wc * 64;
    #pragma unroll
    for (int n = 0; n < 4; ++n) {
        int col = cb0 + n * 16 + lr;
        if (col >= N) continue;
        float bv = bias ? bias[col] : 0.0f;
        #pragma unroll
        for (int m = 0; m < 4; ++m) {
            #pragma unroll
            for (int rr = 0; rr < 4; ++rr) {
                int row = rb0 + m * 16 + (l >> 4) * 4 + rr;
                if (row >= M) continue;
                float c = acc[m][n][rr] + bv;
                if (BF16OUT) ((unsigned short*)Cout)[(size_t)row * ldc + col] = f2bf(c);
                else ((float*)Cout)[(size_t)row * ldc + col] = c;
            }
        }
    }
}

// ---------- flash attention: one block per (b*h, 64-row q tile) ----------
__global__ __launch_bounds__(256) void k_attn(const unsigned short* __restrict__ qkv,
                                              unsigned short* __restrict__ ctx) {
    int bh = blockIdx.x;
    int qt = blockIdx.y;
    int b = bh >> 4, h = bh & 15;
    int tid = threadIdx.x;
    int l = tid & 63;
    int w = tid >> 6;
    int lr = l & 15;
    int lk = (l >> 4) * 8;

    __shared__ unsigned short Qs[64][72];
    __shared__ unsigned short Ks[64][72];
    __shared__ unsigned short Vt[64][72];
    __shared__ unsigned short Ps[64][72];

    const size_t base = (size_t)b * NSEQ * NQKV + (size_t)h * 64;
    int q0 = qt * 64;

    {
        int row = tid >> 2, ds = (tid & 3) * 16;
        int qrow = q0 + row;
        if (qrow < NSEQ) {
            const unsigned short* src = qkv + base + (size_t)qrow * NQKV + ds;
            #pragma unroll
            for (int j = 0; j < 16; ++j) Qs[row][ds + j] = f2bf(bf2f(src[j]) * 0.125f);
        } else {
            #pragma unroll
            for (int j = 0; j < 16; ++j) Qs[row][ds + j] = 0;
        }
    }

    float m_run[4], l_run[4];
    f32x4 o[4];
    #pragma unroll
    for (int r = 0; r < 4; ++r) { m_run[r] = -1e30f; l_run[r] = 0.0f; }
    #pragma unroll
    for (int n = 0; n < 4; ++n) o[n] = (f32x4){0.f, 0.f, 0.f, 0.f};

    for (int kt = 0; kt < 10; ++kt) {
        __syncthreads();
        {
            int row = tid >> 2, ds = (tid & 3) * 16;
            int key = kt * 64 + row;
            if (key < NSEQ) {
                const unsigned short* ksrc = qkv + base + (size_t)key * NQKV + 1024 + ds;
                *(ushort8*)&Ks[row][ds] = *(const ushort8*)ksrc;
                *(ushort8*)&Ks[row][ds + 8] = *(const ushort8*)(ksrc + 8);
                const unsigned short* vsrc = qkv + base + (size_t)key * NQKV + 2048 + ds;
                #pragma unroll
                for (int j = 0; j < 16; ++j) Vt[ds + j][row] = vsrc[j];
            } else {
                ushort8 z = {};
                *(ushort8*)&Ks[row][ds] = z;
                *(ushort8*)&Ks[row][ds + 8] = z;
                #pragma unroll
                for (int j = 0; j < 16; ++j) Vt[ds + j][row] = 0;
            }
        }
        __syncthreads();

        f32x4 s[4];
        #pragma unroll
        for (int n = 0; n < 4; ++n) s[n] = (f32x4){0.f, 0.f, 0.f, 0.f};
        #pragma unroll
        for (int ks = 0; ks < 2; ++ks) {
            bf16x8 qa = *(const bf16x8*)&Qs[w * 16 + lr][ks * 32 + lk];
            #pragma unroll
            for (int n = 0; n < 4; ++n) {
                bf16x8 kb = *(const bf16x8*)&Ks[n * 16 + lr][ks * 32 + lk];
                s[n] = __builtin_amdgcn_mfma_f32_16x16x32_bf16(qa, kb, s[n], 0, 0, 0);
            }
        }
        #pragma unroll
        for (int n = 0; n < 4; ++n) {
            int col = kt * 64 + n * 16 + lr;
            if (col >= NSEQ) {
                #pragma unroll
                for (int r = 0; r < 4; ++r) s[n][r] = -1e30f;
            }
        }
        float tmax[4];
        #pragma unroll
        for (int r = 0; r < 4; ++r)
            tmax[r] = fmaxf(fmaxf(s[0][r], s[1][r]), fmaxf(s[2][r], s[3][r]));
        #pragma unroll
        for (int off = 1; off < 16; off <<= 1) {
            #pragma unroll
            for (int r = 0; r < 4; ++r) tmax[r] = fmaxf(tmax[r], __shfl_xor(tmax[r], off));
        }
        float alpha[4], rs[4];
        #pragma unroll
        for (int r = 0; r < 4; ++r) {
            float mn = fmaxf(m_run[r], tmax[r]);
            alpha[r] = __expf(m_run[r] - mn);
            m_run[r] = mn;
            rs[r] = 0.0f;
        }
        #pragma unroll
        for (int n = 0; n < 4; ++n) {
            #pragma unroll
            for (int r = 0; r < 4; ++r) {
                float p = __expf(s[n][r] - m_run[r]);
                s[n][r] = p;
                rs[r] += p;
            }
        }
        #pragma unroll
        for (int off = 1; off < 16; off <<= 1) {
            #pragma unroll
            for (int r = 0; r < 4; ++r) rs[r] += __shfl_xor(rs[r], off);
        }
        #pragma unroll
        for (int r = 0; r < 4; ++r) l_run[r] = l_run[r] * alpha[r] + rs[r];
        #pragma unroll
        for (int n = 0; n < 4; ++n) {
            #pragma unroll
            for (int r = 0; r < 4; ++r) o[n][r] *= alpha[r];
        }
        #pragma unroll
        for (int n = 0; n < 4; ++n) {
            #pragma unroll
            for (int r = 0; r < 4; ++r)
                Ps[w * 16 + (l >> 4) * 4 + r][n * 16 + lr] = f2bf(s[n][r]);
        }
        __syncthreads();
        #pragma unroll
        for (int ks = 0; ks < 2; ++ks) {
            bf16x8 pa = *(const bf16x8*)&Ps[w * 16 + lr][ks * 32 + lk];
            #pragma unroll
            for (int n = 0; n < 4; ++n) {
                bf16x8 vb = *(const bf16x8*)&Vt[n * 16 + lr][ks * 32 + lk];
                o[n] = __builtin_amdgcn_mfma_f32_16x16x32_bf16(pa, vb, o[n], 0, 0, 0);
            }
        }
    }
    #pragma unroll
    for (int r = 0; r < 4; ++r) {
        int qrow = q0 + w * 16 + (l >> 4) * 4 + r;
        if (qrow < NSEQ) {
            float inv = (l_run[r] > 0.f) ? 1.0f / l_run[r] : 0.0f;
            #pragma unroll
            for (int n = 0; n < 4; ++n)
                ctx[((size_t)b * NSEQ + qrow) * EMB + h * 64 + n * 16 + lr] = f2bf(o[n][r] * inv);
        }
    }
}

extern "C" void kernel_launch(void* const* d_in, const int* in_sizes, int n_in,
                              void* d_out, int out_size, void* d_ws, size_t ws_size,
                              hipStream_t stream) {
    const float* tokens      = (const float*)d_in[0];
    const float* ln1_g       = (const float*)d_in[1];
    const float* ln1_b       = (const float*)d_in[2];
    const float* qkv_w       = (const float*)d_in[3];
    const float* qkv_b       = (const float*)d_in[4];
    const float* proj_w      = (const float*)d_in[5];
    const float* proj_b      = (const float*)d_in[6];
    const float* lora_gate_w = (const float*)d_in[7];
    const float* lora_A      = (const float*)d_in[8];
    const float* lora_B      = (const float*)d_in[9];
    const float* ln2_g       = (const float*)d_in[10];
    const float* ln2_b       = (const float*)d_in[11];
    const float* fc1_w       = (const float*)d_in[12];
    const float* fc1_b       = (const float*)d_in[13];
    const float* fc2_w       = (const float*)d_in[14];
    const float* fc2_b       = (const float*)d_in[15];
    const float* ad_gate_w   = (const float*)d_in[16];
    const float* ad_down_w   = (const float*)d_in[17];
    const float* ad_down_b   = (const float*)d_in[18];
    const float* ad_up_w     = (const float*)d_in[19];
    const float* ad_up_b     = (const float*)d_in[20];

    char* ws = (char*)d_ws;
    size_t off = 0;
    auto alloc = [&](size_t bytes) -> void* {
        void* p = ws + off;
        off += (bytes + 255) & ~(size_t)255;
        return p;
    };

    unsigned short* w_qkvcat = (unsigned short*)alloc((size_t)NQKV * KQKV * 2);
    unsigned short* w_proj   = (unsigned short*)alloc((size_t)EMB * EMB * 2);
    unsigned short* w_fc1    = (unsigned short*)alloc((size_t)FFD * EMB * 2);
    unsigned short* w_fc2cat = (unsigned short*)alloc((size_t)EMB * KFC2 * 2);
    unsigned short* w_acat   = (unsigned short*)alloc((size_t)64 * EMB * 2);
    unsigned short* w_dcat   = (unsigned short*)alloc((size_t)256 * EMB * 2);

    char* buf1 = (char*)alloc((size_t)TOK * KQKV * 2);   // normedcat -> mlpin
    char* buf2 = (char*)alloc((size_t)TOK * KFC2 * 2);   // qkv -> h1cat
    char* buf3 = (char*)alloc((size_t)TOK * EMB * 2);    // ctx -> ahpre
    float* tok2   = (float*)alloc((size_t)TOK * EMB * 4);
    float* lora_h = (float*)alloc((size_t)TOK * 64 * 4);
    float* gates  = (float*)alloc((size_t)TOK * 4 * 4);
    float* ag     = (float*)alloc((size_t)TOK * 4 * 4);

    unsigned short* normedcat = (unsigned short*)buf1;   // [TOK][1088]
    unsigned short* mlpin     = (unsigned short*)buf1;   // [TOK][1024]
    unsigned short* qkv       = (unsigned short*)buf2;   // [TOK][3072]
    unsigned short* h1cat     = (unsigned short*)buf2;   // [TOK][4352]
    unsigned short* ctx       = (unsigned short*)buf3;
    float*          ahpre     = (float*)buf3;

    // ---- weight conversion / packing ----
    k_pack_str<<<(NQKV * EMB + 255) / 256, 256, 0, stream>>>(qkv_w, w_qkvcat, EMB, KQKV, NQKV * EMB);
    k_pack_bcat<<<(NQKV * 64 + 255) / 256, 256, 0, stream>>>(lora_B, w_qkvcat);
    k_pack_str<<<(EMB * EMB + 255) / 256, 256, 0, stream>>>(proj_w, w_proj, EMB, EMB, EMB * EMB);
    k_pack_str<<<(FFD * EMB + 255) / 256, 256, 0, stream>>>(fc1_w, w_fc1, EMB, EMB, FFD * EMB);
    k_pack_str<<<(EMB * FFD + 255) / 256, 256, 0, stream>>>(fc2_w, w_fc2cat, FFD, KFC2, EMB * FFD);
    k_pack_u<<<(EMB * 256 + 255) / 256, 256, 0, stream>>>(ad_up_w, w_fc2cat);
    k_pack_str<<<(64 * EMB + 255) / 256, 256, 0, stream>>>(lora_A, w_acat, EMB, EMB, 64 * EMB);
    k_pack_str<<<(256 * EMB + 255) / 256, 256, 0, stream>>>(ad_down_w, w_dcat, EMB, EMB, 256 * EMB);

    // ---- forward ----
    k_ln_gates<<<TOK, 256, 0, stream>>>(tokens, ln1_g, ln1_b, lora_gate_w, normedcat, KQKV, gates);
    k_gemm128<false><<<73, 256, 0, stream>>>(
        normedcat, KQKV, w_acat, TOK, 64, EMB, nullptr, lora_h, 64, 1);
    k_make_hw<<<(TOK * 64 + 255) / 256, 256, 0, stream>>>(gates, lora_h, normedcat);
    k_gemm256<false, true><<<37 * 12, 512, 0, stream>>>(
        normedcat, w_qkvcat, TOK, NQKV, KQKV, qkv_b, nullptr, qkv, NQKV, 12);
    k_attn<<<dim3(256, 10), 256, 0, stream>>>(qkv, ctx);
    k_gemm256<false, false><<<37 * 4, 512, 0, stream>>>(
        ctx, w_proj, TOK, EMB, EMB, proj_b, tokens, tok2, EMB, 4);
    k_ln_gates<<<TOK, 256, 0, stream>>>(tok2, ln2_g, ln2_b, ad_gate_w, mlpin, EMB, ag);
    k_gemm128<false><<<73 * 2, 256, 0, stream>>>(
        mlpin, EMB, w_dcat, TOK, 256, EMB, ad_down_b, ahpre, 256, 2);
    k_make_ahw<<<(TOK * 256 + 255) / 256, 256, 0, stream>>>(ag, ahpre, h1cat);
    k_adbias<<<TOK, 256, 0, stream>>>(ag, ad_up_b, tok2);
    k_gemm256<true, true><<<37 * 16, 512, 0, stream>>>(
        mlpin, w_fc1, TOK, FFD, EMB, fc1_b, nullptr, h1cat, KFC2, 16);
    k_gemm256<false, false><<<37 * 4, 512, 0, stream>>>(
        h1cat, w_fc2cat, TOK, EMB, KFC2, fc2_b, tok2, d_out, EMB, 4);
}

// Round 6
// 806.386 us; speedup vs baseline: 1.1242x; 1.1242x over previous
//
#include <hip/hip_runtime.h>
#include <math.h>

#define TOK 9232      // B*N = 16*577
#define EMB 1024
#define NQKV 3072
#define FFD 4096
#define NSEQ 577

typedef __bf16 bf16x8 __attribute__((ext_vector_type(8)));
typedef float f32x4 __attribute__((ext_vector_type(4)));
typedef unsigned short ushort8 __attribute__((ext_vector_type(8)));
typedef unsigned short ushort4v __attribute__((ext_vector_type(4)));

typedef __attribute__((address_space(3))) unsigned int lds_u32_t;
typedef const __attribute__((address_space(1))) unsigned int glob_u32_t;

__device__ __forceinline__ void async16(void* lds, const void* g) {
    __builtin_amdgcn_global_load_lds((glob_u32_t*)g, (lds_u32_t*)lds, 16, 0, 0);
}

__device__ __forceinline__ unsigned short f2bf(float f) {
    unsigned int u = __builtin_bit_cast(unsigned int, f);
    u = (u + 0x7fffu + ((u >> 16) & 1u)) >> 16;
    return (unsigned short)u;
}
__device__ __forceinline__ float bf2f(unsigned short s) {
    unsigned int u = ((unsigned int)s) << 16;
    return __builtin_bit_cast(float, u);
}
__device__ __forceinline__ float gelu_exact(float x) {
    return 0.5f * x * (1.0f + erff(x * 0.70710678118654752f));
}

// ---------- merged weight conversion (6 contiguous f32->bf16 segments) ----------
// sizes in float4 units; cum: 786432,1048576,2097152,3145728,3162112,3227648
__global__ void k_pack_all(const float* __restrict__ s_qkv, const float* __restrict__ s_proj,
                           const float* __restrict__ s_fc1, const float* __restrict__ s_fc2,
                           const float* __restrict__ s_la,  const float* __restrict__ s_ad,
                           unsigned short* __restrict__ d_qkv, unsigned short* __restrict__ d_proj,
                           unsigned short* __restrict__ d_fc1, unsigned short* __restrict__ d_fc2,
                           unsigned short* __restrict__ d_la,  unsigned short* __restrict__ d_ad) {
    int stride = gridDim.x * 256;
    for (int i4 = blockIdx.x * 256 + threadIdx.x; i4 < 3227648; i4 += stride) {
        const float* s; unsigned short* d; int local;
        if (i4 < 786432)       { s = s_qkv;  d = d_qkv;  local = i4; }
        else if (i4 < 1048576) { s = s_proj; d = d_proj; local = i4 - 786432; }
        else if (i4 < 2097152) { s = s_fc1;  d = d_fc1;  local = i4 - 1048576; }
        else if (i4 < 3145728) { s = s_fc2;  d = d_fc2;  local = i4 - 2097152; }
        else if (i4 < 3162112) { s = s_la;   d = d_la;   local = i4 - 3145728; }
        else                   { s = s_ad;   d = d_ad;   local = i4 - 3162112; }
        float4 v = ((const float4*)s)[local];
        ushort4v o;
        o[0] = f2bf(v.x); o[1] = f2bf(v.y); o[2] = f2bf(v.z); o[3] = f2bf(v.w);
        ((ushort4v*)d)[local] = o;
    }
}
// lora_B [4][3072][16] -> Bcat[o][x*16+r]
__global__ void k_pack_bcat(const float* __restrict__ Bw, unsigned short* __restrict__ out) {
    int i = blockIdx.x * 256 + threadIdx.x;
    if (i >= 3072 * 64) return;
    int o = i >> 6, j = i & 63, x = j >> 4, r = j & 15;
    out[o * 64 + j] = f2bf(Bw[x * 3072 * 16 + o * 16 + r]);
}
// ad_up_w [4][1024][64] -> U[o][x*64+h]
__global__ void k_pack_u(const float* __restrict__ Uw, unsigned short* __restrict__ out) {
    int i = blockIdx.x * 256 + threadIdx.x;
    if (i >= 1024 * 256) return;
    int o = i >> 8, j = i & 255, x = j >> 6, h = j & 63;
    out[o * 256 + j] = f2bf(Uw[x * 65536 + o * 64 + h]);
}

// ---------- fused layernorm + 4-expert gate softmax, one block per token ----------
__global__ __launch_bounds__(256) void k_ln_gates(const float* __restrict__ x,
                                                  const float* __restrict__ g,
                                                  const float* __restrict__ b,
                                                  const float* __restrict__ gw,
                                                  unsigned short* __restrict__ out,
                                                  float* __restrict__ gates) {
    int t = blockIdx.x;
    int tid = threadIdx.x;
    const float* xp = x + (size_t)t * EMB;
    float4 v = ((const float4*)xp)[tid];
    float s = v.x + v.y + v.z + v.w;
    float sq = v.x * v.x + v.y * v.y + v.z * v.z + v.w * v.w;
    #pragma unroll
    for (int off = 32; off > 0; off >>= 1) {
        s += __shfl_down(s, off);
        sq += __shfl_down(sq, off);
    }
    __shared__ float red[8];
    if ((tid & 63) == 0) { red[tid >> 6] = s; red[(tid >> 6) + 4] = sq; }
    __syncthreads();
    float S = red[0] + red[1] + red[2] + red[3];
    float SQ = red[4] + red[5] + red[6] + red[7];
    float mean = S * (1.0f / EMB);
    float var = SQ * (1.0f / EMB) - mean * mean;
    float rstd = rsqrtf(var + 1e-6f);
    float4 gv = ((const float4*)g)[tid];
    float4 bv = ((const float4*)b)[tid];
    float n0 = (v.x - mean) * rstd * gv.x + bv.x;
    float n1 = (v.y - mean) * rstd * gv.y + bv.y;
    float n2 = (v.z - mean) * rstd * gv.z + bv.z;
    float n3 = (v.w - mean) * rstd * gv.w + bv.w;
    ushort4v o;
    o[0] = f2bf(n0); o[1] = f2bf(n1); o[2] = f2bf(n2); o[3] = f2bf(n3);
    ((ushort4v*)(out + (size_t)t * EMB))[tid] = o;
    float p[4];
    #pragma unroll
    for (int xx = 0; xx < 4; ++xx) {
        float4 gr = ((const float4*)(gw + xx * EMB))[tid];
        p[xx] = n0 * gr.x + n1 * gr.y + n2 * gr.z + n3 * gr.w;
    }
    #pragma unroll
    for (int off = 32; off > 0; off >>= 1) {
        #pragma unroll
        for (int xx = 0; xx < 4; ++xx) p[xx] += __shfl_down(p[xx], off);
    }
    __shared__ float red2[4][4];
    if ((tid & 63) == 0) {
        #pragma unroll
        for (int xx = 0; xx < 4; ++xx) red2[tid >> 6][xx] = p[xx];
    }
    __syncthreads();
    if (tid == 0) {
        float l[4];
        #pragma unroll
        for (int xx = 0; xx < 4; ++xx) l[xx] = red2[0][xx] + red2[1][xx] + red2[2][xx] + red2[3][xx];
        float m = fmaxf(fmaxf(l[0], l[1]), fmaxf(l[2], l[3]));
        float e[4], ssum = 0.f;
        #pragma unroll
        for (int xx = 0; xx < 4; ++xx) { e[xx] = expf(l[xx] - m); ssum += e[xx]; }
        float inv = 1.0f / ssum;
        #pragma unroll
        for (int xx = 0; xx < 4; ++xx) gates[t * 4 + xx] = e[xx] * inv;
    }
}

// d_out[t][o] = tok2[t][o] + fc2_b[o] + sum_x ag[t][x] * ad_up_b[x][o]
__global__ __launch_bounds__(256) void k_fc2init(const float* __restrict__ tok2,
                                                 const float* __restrict__ fc2b,
                                                 const float* __restrict__ ag,
                                                 const float* __restrict__ upb,
                                                 float* __restrict__ out) {
    int t = blockIdx.x;
    int tid = threadIdx.x;
    float g0 = ag[t * 4 + 0], g1 = ag[t * 4 + 1], g2 = ag[t * 4 + 2], g3 = ag[t * 4 + 3];
    float4 b0 = ((const float4*)(upb + 0 * EMB))[tid];
    float4 b1 = ((const float4*)(upb + 1 * EMB))[tid];
    float4 b2 = ((const float4*)(upb + 2 * EMB))[tid];
    float4 b3 = ((const float4*)(upb + 3 * EMB))[tid];
    float4 fb = ((const float4*)fc2b)[tid];
    float4 r = ((const float4*)(tok2 + (size_t)t * EMB))[tid];
    r.x += fb.x + g0 * b0.x + g1 * b1.x + g2 * b2.x + g3 * b3.x;
    r.y += fb.y + g0 * b0.y + g1 * b1.y + g2 * b2.y + g3 * b3.y;
    r.z += fb.z + g0 * b0.z + g1 * b1.z + g2 * b2.z + g3 * b3.z;
    r.w += fb.w + g0 * b0.w + g1 * b1.w + g2 * b2.w + g3 * b3.w;
    ((float4*)(out + (size_t)t * EMB))[tid] = r;
}

// ---------- MFMA GEMM (m97 structure, 128x128, BK=32) ----------
// C[M,N] = A[.,koff:koff+klen]@W[.,koff:koff+klen]^T (+A2@W2^T on last kslice)
// epilogue: +bias -> GELU? -> *aux gate (GG cols/group)? -> +resid? -> store (atomic/bf16/f32)
template<bool GELU, bool BF16OUT, bool ATOMIC, int GG, int KS>
__global__ __launch_bounds__(256) void k_gemm(
    const unsigned short* __restrict__ A, int lda,
    const unsigned short* __restrict__ W, int ldw, int klen,
    int M, int N,
    const unsigned short* __restrict__ A2, const unsigned short* __restrict__ W2, int K2,
    const float* __restrict__ bias, const float* __restrict__ resid,
    const float* __restrict__ aux,
    void* __restrict__ Cout, int ldc, int gy)
{
    __shared__ unsigned short As[128][32];
    __shared__ unsigned short Ws[128][32];
    int tid = threadIdx.x;
    int nwg = gridDim.x, orig = blockIdx.x;
    int xcd = orig & 7, lid = orig >> 3;
    int q = nwg >> 3, r = nwg & 7;
    int wg = (xcd < r ? xcd * (q + 1) : r * (q + 1) + (xcd - r) * q) + lid;
    int mt = wg / gy, nk = wg - mt * gy;
    int nt = nk / KS, ks = nk - nt * KS;
    int bm128 = mt * 128;
    int bn128 = nt * 128;
    int koff = ks * klen;

    int l = tid & 63, w = tid >> 6;
    int wr = w >> 1, wc = w & 1;
    int lr = l & 15, lk = (l >> 4) * 8;
    int srow = l >> 2;
    int sslot = (l & 3) * 8;

    f32x4 acc[4][4];
    #pragma unroll
    for (int m = 0; m < 4; ++m)
        #pragma unroll
        for (int n = 0; n < 4; ++n) acc[m][n] = (f32x4){0.f, 0.f, 0.f, 0.f};

    auto kloop = [&](const unsigned short* __restrict__ Ap, int sA,
                     const unsigned short* __restrict__ Wp, int sW, int Kc) {
        for (int k0 = 0; k0 < Kc; k0 += 32) {
            #pragma unroll
            for (int i = 0; i < 2; ++i) {
                int row = w * 32 + i * 16 + srow;
                int ra = bm128 + row; if (ra >= M) ra = M - 1;
                async16((char*)&As[0][0] + w * 2048 + i * 1024,
                        Ap + (size_t)ra * sA + k0 + sslot);
                int rb = bn128 + row; if (rb >= N) rb = N - 1;
                async16((char*)&Ws[0][0] + w * 2048 + i * 1024,
                        Wp + (size_t)rb * sW + k0 + sslot);
            }
            __syncthreads();
            bf16x8 af[4], bfr[4];
            #pragma unroll
            for (int m = 0; m < 4; ++m) af[m] = *(const bf16x8*)&As[wr * 64 + m * 16 + lr][lk];
            #pragma unroll
            for (int n = 0; n < 4; ++n) bfr[n] = *(const bf16x8*)&Ws[wc * 64 + n * 16 + lr][lk];
            #pragma unroll
            for (int m = 0; m < 4; ++m)
                #pragma unroll
                for (int n = 0; n < 4; ++n)
                    acc[m][n] = __builtin_amdgcn_mfma_f32_16x16x32_bf16(af[m], bfr[n], acc[m][n], 0, 0, 0);
            __syncthreads();
        }
    };
    kloop(A + koff, lda, W + koff, ldw, klen);
    if (A2 && ks == KS - 1) kloop(A2, K2, W2, K2, K2);

    int rb0 = bm128 + wr * 64;
    int cb0 = bn128 + wc * 64;
    #pragma unroll
    for (int n = 0; n < 4; ++n) {
        int col = cb0 + n * 16 + lr;
        if (col >= N) continue;
        float bv = bias ? bias[col] : 0.0f;
        #pragma unroll
        for (int m = 0; m < 4; ++m) {
            #pragma unroll
            for (int rr = 0; rr < 4; ++rr) {
                int row = rb0 + m * 16 + (l >> 4) * 4 + rr;
                if (row >= M) continue;
                float c = acc[m][n][rr] + bv;
                if (GELU) c = gelu_exact(c);
                if (GG > 0) c *= aux[row * 4 + col / (GG > 0 ? GG : 1)];
                if (resid) c += resid[(size_t)row * ldc + col];
                if (ATOMIC) {
                    unsafeAtomicAdd((float*)Cout + (size_t)row * ldc + col, c);
                } else if (BF16OUT) {
                    ((unsigned short*)Cout)[(size_t)row * ldc + col] = f2bf(c);
                } else {
                    ((float*)Cout)[(size_t)row * ldc + col] = c;
                }
            }
        }
    }
}

// ---------- flash attention: one block per (b*h, 64-row q tile) ----------
__global__ __launch_bounds__(256) void k_attn(const unsigned short* __restrict__ qkv,
                                              unsigned short* __restrict__ ctx) {
    int bh = blockIdx.x;
    int qt = blockIdx.y;
    int b = bh >> 4, h = bh & 15;
    int tid = threadIdx.x;
    int l = tid & 63;
    int w = tid >> 6;
    int lr = l & 15;
    int lk = (l >> 4) * 8;

    __shared__ unsigned short Qs[64][72];
    __shared__ unsigned short Ks[64][72];
    __shared__ unsigned short Vt[64][72];
    __shared__ unsigned short Ps[64][72];

    const size_t base = (size_t)b * NSEQ * NQKV + (size_t)h * 64;
    int q0 = qt * 64;

    {
        int row = tid >> 2, ds = (tid & 3) * 16;
        int qrow = q0 + row;
        if (qrow < NSEQ) {
            const unsigned short* src = qkv + base + (size_t)qrow * NQKV + ds;
            #pragma unroll
            for (int j = 0; j < 16; ++j) Qs[row][ds + j] = f2bf(bf2f(src[j]) * 0.125f);
        } else {
            #pragma unroll
            for (int j = 0; j < 16; ++j) Qs[row][ds + j] = 0;
        }
    }

    float m_run[4], l_run[4];
    f32x4 o[4];
    #pragma unroll
    for (int r = 0; r < 4; ++r) { m_run[r] = -1e30f; l_run[r] = 0.0f; }
    #pragma unroll
    for (int n = 0; n < 4; ++n) o[n] = (f32x4){0.f, 0.f, 0.f, 0.f};

    for (int kt = 0; kt < 10; ++kt) {
        __syncthreads();
        {
            int row = tid >> 2, ds = (tid & 3) * 16;
            int key = kt * 64 + row;
            if (key < NSEQ) {
                const unsigned short* ksrc = qkv + base + (size_t)key * NQKV + 1024 + ds;
                *(ushort8*)&Ks[row][ds] = *(const ushort8*)ksrc;
                *(ushort8*)&Ks[row][ds + 8] = *(const ushort8*)(ksrc + 8);
                const unsigned short* vsrc = qkv + base + (size_t)key * NQKV + 2048 + ds;
                #pragma unroll
                for (int j = 0; j < 16; ++j) Vt[ds + j][row] = vsrc[j];
            } else {
                ushort8 z = {};
                *(ushort8*)&Ks[row][ds] = z;
                *(ushort8*)&Ks[row][ds + 8] = z;
                #pragma unroll
                for (int j = 0; j < 16; ++j) Vt[ds + j][row] = 0;
            }
        }
        __syncthreads();

        f32x4 s[4];
        #pragma unroll
        for (int n = 0; n < 4; ++n) s[n] = (f32x4){0.f, 0.f, 0.f, 0.f};
        #pragma unroll
        for (int ks = 0; ks < 2; ++ks) {
            bf16x8 qa = *(const bf16x8*)&Qs[w * 16 + lr][ks * 32 + lk];
            #pragma unroll
            for (int n = 0; n < 4; ++n) {
                bf16x8 kb = *(const bf16x8*)&Ks[n * 16 + lr][ks * 32 + lk];
                s[n] = __builtin_amdgcn_mfma_f32_16x16x32_bf16(qa, kb, s[n], 0, 0, 0);
            }
        }
        #pragma unroll
        for (int n = 0; n < 4; ++n) {
            int col = kt * 64 + n * 16 + lr;
            if (col >= NSEQ) {
                #pragma unroll
                for (int r = 0; r < 4; ++r) s[n][r] = -1e30f;
            }
        }
        float tmax[4];
        #pragma unroll
        for (int r = 0; r < 4; ++r)
            tmax[r] = fmaxf(fmaxf(s[0][r], s[1][r]), fmaxf(s[2][r], s[3][r]));
        #pragma unroll
        for (int off = 1; off < 16; off <<= 1) {
            #pragma unroll
            for (int r = 0; r < 4; ++r) tmax[r] = fmaxf(tmax[r], __shfl_xor(tmax[r], off));
        }
        float alpha[4], rs[4];
        #pragma unroll
        for (int r = 0; r < 4; ++r) {
            float mn = fmaxf(m_run[r], tmax[r]);
            alpha[r] = __expf(m_run[r] - mn);
            m_run[r] = mn;
            rs[r] = 0.0f;
        }
        #pragma unroll
        for (int n = 0; n < 4; ++n) {
            #pragma unroll
            for (int r = 0; r < 4; ++r) {
                float p = __expf(s[n][r] - m_run[r]);
                s[n][r] = p;
                rs[r] += p;
            }
        }
        #pragma unroll
        for (int off = 1; off < 16; off <<= 1) {
            #pragma unroll
            for (int r = 0; r < 4; ++r) rs[r] += __shfl_xor(rs[r], off);
        }
        #pragma unroll
        for (int r = 0; r < 4; ++r) l_run[r] = l_run[r] * alpha[r] + rs[r];
        #pragma unroll
        for (int n = 0; n < 4; ++n) {
            #pragma unroll
            for (int r = 0; r < 4; ++r) o[n][r] *= alpha[r];
        }
        #pragma unroll
        for (int n = 0; n < 4; ++n) {
            #pragma unroll
            for (int r = 0; r < 4; ++r)
                Ps[w * 16 + (l >> 4) * 4 + r][n * 16 + lr] = f2bf(s[n][r]);
        }
        __syncthreads();
        #pragma unroll
        for (int ks = 0; ks < 2; ++ks) {
            bf16x8 pa = *(const bf16x8*)&Ps[w * 16 + lr][ks * 32 + lk];
            #pragma unroll
            for (int n = 0; n < 4; ++n) {
                bf16x8 vb = *(const bf16x8*)&Vt[n * 16 + lr][ks * 32 + lk];
                o[n] = __builtin_amdgcn_mfma_f32_16x16x32_bf16(pa, vb, o[n], 0, 0, 0);
            }
        }
    }
    #pragma unroll
    for (int r = 0; r < 4; ++r) {
        int qrow = q0 + w * 16 + (l >> 4) * 4 + r;
        if (qrow < NSEQ) {
            float inv = (l_run[r] > 0.f) ? 1.0f / l_run[r] : 0.0f;
            #pragma unroll
            for (int n = 0; n < 4; ++n)
                ctx[((size_t)b * NSEQ + qrow) * EMB + h * 64 + n * 16 + lr] = f2bf(o[n][r] * inv);
        }
    }
}

extern "C" void kernel_launch(void* const* d_in, const int* in_sizes, int n_in,
                              void* d_out, int out_size, void* d_ws, size_t ws_size,
                              hipStream_t stream) {
    const float* tokens      = (const float*)d_in[0];
    const float* ln1_g       = (const float*)d_in[1];
    const float* ln1_b       = (const float*)d_in[2];
    const float* qkv_w       = (const float*)d_in[3];
    const float* qkv_b       = (const float*)d_in[4];
    const float* proj_w      = (const float*)d_in[5];
    const float* proj_b      = (const float*)d_in[6];
    const float* lora_gate_w = (const float*)d_in[7];
    const float* lora_A      = (const float*)d_in[8];
    const float* lora_B      = (const float*)d_in[9];
    const float* ln2_g       = (const float*)d_in[10];
    const float* ln2_b       = (const float*)d_in[11];
    const float* fc1_w       = (const float*)d_in[12];
    const float* fc1_b       = (const float*)d_in[13];
    const float* fc2_w       = (const float*)d_in[14];
    const float* fc2_b       = (const float*)d_in[15];
    const float* ad_gate_w   = (const float*)d_in[16];
    const float* ad_down_w   = (const float*)d_in[17];
    const float* ad_down_b   = (const float*)d_in[18];
    const float* ad_up_w     = (const float*)d_in[19];
    const float* ad_up_b     = (const float*)d_in[20];

    char* ws = (char*)d_ws;
    size_t off = 0;
    auto alloc = [&](size_t bytes) -> void* {
        void* p = ws + off;
        off += (bytes + 255) & ~(size_t)255;
        return p;
    };

    unsigned short* w_qkv  = (unsigned short*)alloc((size_t)NQKV * EMB * 2);
    unsigned short* w_proj = (unsigned short*)alloc((size_t)EMB * EMB * 2);
    unsigned short* w_fc1  = (unsigned short*)alloc((size_t)FFD * EMB * 2);
    unsigned short* w_fc2  = (unsigned short*)alloc((size_t)EMB * FFD * 2);
    unsigned short* w_acat = (unsigned short*)alloc((size_t)64 * EMB * 2);
    unsigned short* w_bcat = (unsigned short*)alloc((size_t)NQKV * 64 * 2);
    unsigned short* w_dcat = (unsigned short*)alloc((size_t)256 * EMB * 2);
    unsigned short* w_u    = (unsigned short*)alloc((size_t)EMB * 256 * 2);

    unsigned short* u1 = (unsigned short*)alloc((size_t)TOK * EMB * 2);  // normed -> mlpin
    unsigned short* u2 = (unsigned short*)alloc((size_t)TOK * EMB * 2);  // ctx
    unsigned short* u3 = (unsigned short*)alloc((size_t)TOK * FFD * 2);  // qkv -> h1
    float* tok2  = (float*)alloc((size_t)TOK * EMB * 4);
    unsigned short* hw  = (unsigned short*)alloc((size_t)TOK * 64 * 2);
    unsigned short* ahw = (unsigned short*)alloc((size_t)TOK * 256 * 2);
    float* gates = (float*)alloc((size_t)TOK * 4 * 4);
    float* ag    = (float*)alloc((size_t)TOK * 4 * 4);

    unsigned short* normed = u1;
    unsigned short* mlpin  = u1;
    unsigned short* ctx    = u2;
    unsigned short* qkv    = u3;
    unsigned short* h1     = u3;

    // ---- weight conversion / packing (3 dispatches) ----
    k_pack_all<<<2048, 256, 0, stream>>>(qkv_w, proj_w, fc1_w, fc2_w, lora_A, ad_down_w,
                                         w_qkv, w_proj, w_fc1, w_fc2, w_acat, w_dcat);
    k_pack_bcat<<<(NQKV * 64 + 255) / 256, 256, 0, stream>>>(lora_B, w_bcat);
    k_pack_u<<<(EMB * 256 + 255) / 256, 256, 0, stream>>>(ad_up_w, w_u);

    // ---- forward ----
    k_ln_gates<<<TOK, 256, 0, stream>>>(tokens, ln1_g, ln1_b, lora_gate_w, normed, gates);
    // lora down: hw = gates * (normed @ lora_A^T), bf16 out, gate group 16
    k_gemm<false, true, false, 16, 1><<<73, 256, 0, stream>>>(
        normed, EMB, w_acat, EMB, EMB, TOK, 64,
        nullptr, nullptr, 0, nullptr, nullptr, gates, hw, 64, 1);
    // qkv = normed @ qkv_w^T + hw @ bcat^T + qkv_b
    k_gemm<false, true, false, 0, 1><<<73 * 24, 256, 0, stream>>>(
        normed, EMB, w_qkv, EMB, EMB, TOK, NQKV,
        hw, w_bcat, 64, qkv_b, nullptr, nullptr, qkv, NQKV, 24);
    k_attn<<<dim3(256, 10), 256, 0, stream>>>(qkv, ctx);
    // tok2 = tokens + ctx @ proj^T + proj_b   (fp32)
    k_gemm<false, false, false, 0, 1><<<73 * 8, 256, 0, stream>>>(
        ctx, EMB, w_proj, EMB, EMB, TOK, EMB,
        nullptr, nullptr, 0, proj_b, tokens, nullptr, tok2, EMB, 8);
    k_ln_gates<<<TOK, 256, 0, stream>>>(tok2, ln2_g, ln2_b, ad_gate_w, mlpin, ag);
    // adapter down: ahw = ag * gelu(mlpin @ d^T + db), bf16, gate group 64
    k_gemm<true, true, false, 64, 1><<<73 * 2, 256, 0, stream>>>(
        mlpin, EMB, w_dcat, EMB, EMB, TOK, 256,
        nullptr, nullptr, 0, ad_down_b, nullptr, ag, ahw, 256, 2);
    // d_out = tok2 + fc2_b + ag @ ad_up_b
    k_fc2init<<<TOK, 256, 0, stream>>>(tok2, fc2_b, ag, ad_up_b, (float*)d_out);
    // h1 = gelu(mlpin @ fc1^T + fc1_b)
    k_gemm<true, true, false, 0, 1><<<73 * 32, 256, 0, stream>>>(
        mlpin, EMB, w_fc1, EMB, EMB, TOK, FFD,
        nullptr, nullptr, 0, fc1_b, nullptr, nullptr, h1, FFD, 32);
    // d_out += h1 @ fc2^T + ahw @ u^T   (split-K x2, atomic fp32)
    k_gemm<false, false, true, 0, 2><<<73 * 16, 256, 0, stream>>>(
        h1, FFD, w_fc2, FFD, 2048, TOK, EMB,
        ahw, w_u, 256, nullptr, nullptr, nullptr, (float*)d_out, EMB, 16);
}

// Round 7
// 739.418 us; speedup vs baseline: 1.2260x; 1.0906x over previous
//
#include <hip/hip_runtime.h>
#include <math.h>

#define TOK 9232      // B*N = 16*577
#define EMB 1024
#define NQKV 3072
#define FFD 4096
#define NSEQ 577

typedef __bf16 bf16x8 __attribute__((ext_vector_type(8)));
typedef float f32x4 __attribute__((ext_vector_type(4)));
typedef unsigned short ushort8 __attribute__((ext_vector_type(8)));
typedef unsigned short ushort4v __attribute__((ext_vector_type(4)));

typedef __attribute__((address_space(3))) unsigned int lds_u32_t;
typedef const __attribute__((address_space(1))) unsigned int glob_u32_t;

__device__ __forceinline__ void async16(void* lds, const void* g) {
    __builtin_amdgcn_global_load_lds((glob_u32_t*)g, (lds_u32_t*)lds, 16, 0, 0);
}

__device__ __forceinline__ unsigned short f2bf(float f) {
    unsigned int u = __builtin_bit_cast(unsigned int, f);
    u = (u + 0x7fffu + ((u >> 16) & 1u)) >> 16;
    return (unsigned short)u;
}
__device__ __forceinline__ float bf2f(unsigned short s) {
    unsigned int u = ((unsigned int)s) << 16;
    return __builtin_bit_cast(float, u);
}
__device__ __forceinline__ float gelu_exact(float x) {
    return 0.5f * x * (1.0f + erff(x * 0.70710678118654752f));
}

// ---------- merged weight conversion (6 contiguous f32->bf16 segments) ----------
__global__ void k_pack_all(const float* __restrict__ s_qkv, const float* __restrict__ s_proj,
                           const float* __restrict__ s_fc1, const float* __restrict__ s_fc2,
                           const float* __restrict__ s_la,  const float* __restrict__ s_ad,
                           unsigned short* __restrict__ d_qkv, unsigned short* __restrict__ d_proj,
                           unsigned short* __restrict__ d_fc1, unsigned short* __restrict__ d_fc2,
                           unsigned short* __restrict__ d_la,  unsigned short* __restrict__ d_ad) {
    int stride = gridDim.x * 256;
    for (int i4 = blockIdx.x * 256 + threadIdx.x; i4 < 3227648; i4 += stride) {
        const float* s; unsigned short* d; int local;
        if (i4 < 786432)       { s = s_qkv;  d = d_qkv;  local = i4; }
        else if (i4 < 1048576) { s = s_proj; d = d_proj; local = i4 - 786432; }
        else if (i4 < 2097152) { s = s_fc1;  d = d_fc1;  local = i4 - 1048576; }
        else if (i4 < 3145728) { s = s_fc2;  d = d_fc2;  local = i4 - 2097152; }
        else if (i4 < 3162112) { s = s_la;   d = d_la;   local = i4 - 3145728; }
        else                   { s = s_ad;   d = d_ad;   local = i4 - 3162112; }
        float4 v = ((const float4*)s)[local];
        ushort4v o;
        o[0] = f2bf(v.x); o[1] = f2bf(v.y); o[2] = f2bf(v.z); o[3] = f2bf(v.w);
        ((ushort4v*)d)[local] = o;
    }
}
// lora_B [4][3072][16] -> Bcat[o][x*16+r]
__global__ void k_pack_bcat(const float* __restrict__ Bw, unsigned short* __restrict__ out) {
    int i = blockIdx.x * 256 + threadIdx.x;
    if (i >= 3072 * 64) return;
    int o = i >> 6, j = i & 63, x = j >> 4, r = j & 15;
    out[o * 64 + j] = f2bf(Bw[x * 3072 * 16 + o * 16 + r]);
}
// ad_up_w [4][1024][64] -> U[o][x*64+h]
__global__ void k_pack_u(const float* __restrict__ Uw, unsigned short* __restrict__ out) {
    int i = blockIdx.x * 256 + threadIdx.x;
    if (i >= 1024 * 256) return;
    int o = i >> 8, j = i & 255, x = j >> 6, h = j & 63;
    out[o * 256 + j] = f2bf(Uw[x * 65536 + o * 64 + h]);
}

// ---------- fused layernorm + 4-expert gate softmax, one block per token ----------
__global__ __launch_bounds__(256) void k_ln_gates(const float* __restrict__ x,
                                                  const float* __restrict__ g,
                                                  const float* __restrict__ b,
                                                  const float* __restrict__ gw,
                                                  unsigned short* __restrict__ out,
                                                  float* __restrict__ gates) {
    int t = blockIdx.x;
    int tid = threadIdx.x;
    const float* xp = x + (size_t)t * EMB;
    float4 v = ((const float4*)xp)[tid];
    float s = v.x + v.y + v.z + v.w;
    float sq = v.x * v.x + v.y * v.y + v.z * v.z + v.w * v.w;
    #pragma unroll
    for (int off = 32; off > 0; off >>= 1) {
        s += __shfl_down(s, off);
        sq += __shfl_down(sq, off);
    }
    __shared__ float red[8];
    if ((tid & 63) == 0) { red[tid >> 6] = s; red[(tid >> 6) + 4] = sq; }
    __syncthreads();
    float S = red[0] + red[1] + red[2] + red[3];
    float SQ = red[4] + red[5] + red[6] + red[7];
    float mean = S * (1.0f / EMB);
    float var = SQ * (1.0f / EMB) - mean * mean;
    float rstd = rsqrtf(var + 1e-6f);
    float4 gv = ((const float4*)g)[tid];
    float4 bv = ((const float4*)b)[tid];
    float n0 = (v.x - mean) * rstd * gv.x + bv.x;
    float n1 = (v.y - mean) * rstd * gv.y + bv.y;
    float n2 = (v.z - mean) * rstd * gv.z + bv.z;
    float n3 = (v.w - mean) * rstd * gv.w + bv.w;
    ushort4v o;
    o[0] = f2bf(n0); o[1] = f2bf(n1); o[2] = f2bf(n2); o[3] = f2bf(n3);
    ((ushort4v*)(out + (size_t)t * EMB))[tid] = o;
    float p[4];
    #pragma unroll
    for (int xx = 0; xx < 4; ++xx) {
        float4 gr = ((const float4*)(gw + xx * EMB))[tid];
        p[xx] = n0 * gr.x + n1 * gr.y + n2 * gr.z + n3 * gr.w;
    }
    #pragma unroll
    for (int off = 32; off > 0; off >>= 1) {
        #pragma unroll
        for (int xx = 0; xx < 4; ++xx) p[xx] += __shfl_down(p[xx], off);
    }
    __shared__ float red2[4][4];
    if ((tid & 63) == 0) {
        #pragma unroll
        for (int xx = 0; xx < 4; ++xx) red2[tid >> 6][xx] = p[xx];
    }
    __syncthreads();
    if (tid == 0) {
        float l[4];
        #pragma unroll
        for (int xx = 0; xx < 4; ++xx) l[xx] = red2[0][xx] + red2[1][xx] + red2[2][xx] + red2[3][xx];
        float m = fmaxf(fmaxf(l[0], l[1]), fmaxf(l[2], l[3]));
        float e[4], ssum = 0.f;
        #pragma unroll
        for (int xx = 0; xx < 4; ++xx) { e[xx] = expf(l[xx] - m); ssum += e[xx]; }
        float inv = 1.0f / ssum;
        #pragma unroll
        for (int xx = 0; xx < 4; ++xx) gates[t * 4 + xx] = e[xx] * inv;
    }
}

// d_out[t][o] = tok2[t][o] + fc2_b[o] + sum_x ag[t][x] * ad_up_b[x][o]
__global__ __launch_bounds__(256) void k_fc2init(const float* __restrict__ tok2,
                                                 const float* __restrict__ fc2b,
                                                 const float* __restrict__ ag,
                                                 const float* __restrict__ upb,
                                                 float* __restrict__ out) {
    int t = blockIdx.x;
    int tid = threadIdx.x;
    float g0 = ag[t * 4 + 0], g1 = ag[t * 4 + 1], g2 = ag[t * 4 + 2], g3 = ag[t * 4 + 3];
    float4 b0 = ((const float4*)(upb + 0 * EMB))[tid];
    float4 b1 = ((const float4*)(upb + 1 * EMB))[tid];
    float4 b2 = ((const float4*)(upb + 2 * EMB))[tid];
    float4 b3 = ((const float4*)(upb + 3 * EMB))[tid];
    float4 fb = ((const float4*)fc2b)[tid];
    float4 r = ((const float4*)(tok2 + (size_t)t * EMB))[tid];
    r.x += fb.x + g0 * b0.x + g1 * b1.x + g2 * b2.x + g3 * b3.x;
    r.y += fb.y + g0 * b0.y + g1 * b1.y + g2 * b2.y + g3 * b3.y;
    r.z += fb.z + g0 * b0.z + g1 * b1.z + g2 * b2.z + g3 * b3.z;
    r.w += fb.w + g0 * b0.w + g1 * b1.w + g2 * b2.w + g3 * b3.w;
    ((float4*)(out + (size_t)t * EMB))[tid] = r;
}

// ---------- MFMA GEMM: 128x128 tile, BK=32, 3-buffer LDS ring, counted vmcnt(8) ----------
// C = A[M,K1]@W[N,K1]^T (+ A2[M,K2]@W2[N,K2]^T) (+bias)(gelu?)(*aux GG?)(+resid)
#define VMCNT8 asm volatile("s_waitcnt vmcnt(8)" ::: "memory")
#define BAR __builtin_amdgcn_s_barrier()

template<bool GELU, bool BF16OUT, int GG>
__global__ __launch_bounds__(256) void k_gemm(
    const unsigned short* __restrict__ A, int lda,
    const unsigned short* __restrict__ W, int ldw, int K1,
    int M, int N,
    const unsigned short* __restrict__ A2, const unsigned short* __restrict__ W2, int K2,
    const float* __restrict__ bias, const float* __restrict__ resid,
    const float* __restrict__ aux,
    void* __restrict__ Cout, int ldc, int gy)
{
    __shared__ unsigned short As[3][128][32];
    __shared__ unsigned short Ws[3][128][32];
    int tid = threadIdx.x;
    int nwg = gridDim.x, orig = blockIdx.x;
    int xcd = orig & 7, lid = orig >> 3;
    int q = nwg >> 3, r = nwg & 7;
    int wg = (xcd < r ? xcd * (q + 1) : r * (q + 1) + (xcd - r) * q) + lid;
    int bm128 = (wg / gy) * 128;
    int bn128 = (wg % gy) * 128;

    int l = tid & 63, w = tid >> 6;
    int wr = w >> 1, wc = w & 1;
    int lr = l & 15, lk = (l >> 4) * 8;
    int srow = l >> 2;
    int sslot = (l & 3) * 8;

    int KT1 = K1 >> 5, KT2 = K2 >> 5;
    int KT = KT1 + KT2;

    // per-thread staging source pointers (rows clamped; garbage feeds only dead rows/cols)
    int ra0 = bm128 + w * 32 + srow;      if (ra0 > M - 1) ra0 = M - 1;
    int ra1 = bm128 + w * 32 + 16 + srow; if (ra1 > M - 1) ra1 = M - 1;
    int rb0 = bn128 + w * 32 + srow;      if (rb0 > N - 1) rb0 = N - 1;
    int rb1 = bn128 + w * 32 + 16 + srow; if (rb1 > N - 1) rb1 = N - 1;
    const unsigned short* pA0 = A + (size_t)ra0 * lda + sslot;
    const unsigned short* pA1 = A + (size_t)ra1 * lda + sslot;
    const unsigned short* pB0 = W + (size_t)rb0 * ldw + sslot;
    const unsigned short* pB1 = W + (size_t)rb1 * ldw + sslot;
    const unsigned short* A2s = A2 ? A2 : A;
    const unsigned short* W2s = W2 ? W2 : W;
    int K2s = A2 ? K2 : lda;
    const unsigned short* qA0 = A2s + (size_t)ra0 * K2s + sslot;
    const unsigned short* qA1 = A2s + (size_t)ra1 * K2s + sslot;
    const unsigned short* qB0 = W2s + (size_t)rb0 * K2s + sslot;
    const unsigned short* qB1 = W2s + (size_t)rb1 * K2s + sslot;

    f32x4 acc[4][4];
    #pragma unroll
    for (int m = 0; m < 4; ++m)
        #pragma unroll
        for (int n = 0; n < 4; ++n) acc[m][n] = (f32x4){0.f, 0.f, 0.f, 0.f};

#define STAGE(s_, sb_) do {                                          \
    char* da_ = (char*)As + (sb_) * 8192 + w * 2048;                 \
    char* db_ = (char*)Ws + (sb_) * 8192 + w * 2048;                 \
    int ss_ = (s_);                                                  \
    if (ss_ < KT1) {                                                 \
        int ko_ = ss_ << 5;                                          \
        async16(da_,        pA0 + ko_);                              \
        async16(da_ + 1024, pA1 + ko_);                              \
        async16(db_,        pB0 + ko_);                              \
        async16(db_ + 1024, pB1 + ko_);                              \
    } else {                                                         \
        int ko_ = (ss_ - KT1) << 5;                                  \
        async16(da_,        qA0 + ko_);                              \
        async16(da_ + 1024, qA1 + ko_);                              \
        async16(db_,        qB0 + ko_);                              \
        async16(db_ + 1024, qB1 + ko_);                              \
    }                                                                \
} while (0)

    STAGE(0, 0);
    STAGE(1, 1);

    int cb = 0, sb = 2;
    #pragma unroll 1
    for (int t = 0; t < KT; ++t) {
        int s = t + 2; if (s >= KT) s = 0;   // wrap re-stage: buffer never read
        STAGE(s, sb);
        VMCNT8;   // tiles t+1,t+2 (8 loads) stay in flight; tile t complete
        BAR;
        bf16x8 af[4], bfr[4];
        #pragma unroll
        for (int m = 0; m < 4; ++m) af[m] = *(const bf16x8*)&As[cb][wr * 64 + m * 16 + lr][lk];
        #pragma unroll
        for (int n = 0; n < 4; ++n) bfr[n] = *(const bf16x8*)&Ws[cb][wc * 64 + n * 16 + lr][lk];
        __builtin_amdgcn_s_setprio(1);
        #pragma unroll
        for (int m = 0; m < 4; ++m)
            #pragma unroll
            for (int n = 0; n < 4; ++n)
                acc[m][n] = __builtin_amdgcn_mfma_f32_16x16x32_bf16(af[m], bfr[n], acc[m][n], 0, 0, 0);
        __builtin_amdgcn_s_setprio(0);
        BAR;      // all waves done reading buf cb before it is re-staged (2 iters later)
        cb = (cb == 2) ? 0 : cb + 1;
        sb = (sb == 2) ? 0 : sb + 1;
    }
#undef STAGE

    int rbase = bm128 + wr * 64;
    int cbase = bn128 + wc * 64;
    #pragma unroll
    for (int n = 0; n < 4; ++n) {
        int col = cbase + n * 16 + lr;
        if (col >= N) continue;
        float bv = bias ? bias[col] : 0.0f;
        #pragma unroll
        for (int m = 0; m < 4; ++m) {
            #pragma unroll
            for (int rr = 0; rr < 4; ++rr) {
                int row = rbase + m * 16 + (l >> 4) * 4 + rr;
                if (row >= M) continue;
                float c = acc[m][n][rr] + bv;
                if (GELU) c = gelu_exact(c);
                if (GG > 0) c *= aux[row * 4 + col / (GG > 0 ? GG : 1)];
                if (resid) c += resid[(size_t)row * ldc + col];
                if (BF16OUT) ((unsigned short*)Cout)[(size_t)row * ldc + col] = f2bf(c);
                else ((float*)Cout)[(size_t)row * ldc + col] = c;
            }
        }
    }
}

// ---------- flash attention: one block per (b*h, 64-row q tile) ----------
__global__ __launch_bounds__(256) void k_attn(const unsigned short* __restrict__ qkv,
                                              unsigned short* __restrict__ ctx) {
    int bh = blockIdx.x;
    int qt = blockIdx.y;
    int b = bh >> 4, h = bh & 15;
    int tid = threadIdx.x;
    int l = tid & 63;
    int w = tid >> 6;
    int lr = l & 15;
    int lk = (l >> 4) * 8;

    __shared__ unsigned short Qs[64][72];
    __shared__ unsigned short Ks[64][72];
    __shared__ unsigned short Vt[64][72];
    __shared__ unsigned short Ps[64][72];

    const size_t base = (size_t)b * NSEQ * NQKV + (size_t)h * 64;
    int q0 = qt * 64;

    {
        int row = tid >> 2, ds = (tid & 3) * 16;
        int qrow = q0 + row;
        if (qrow < NSEQ) {
            const unsigned short* src = qkv + base + (size_t)qrow * NQKV + ds;
            #pragma unroll
            for (int j = 0; j < 16; ++j) Qs[row][ds + j] = f2bf(bf2f(src[j]) * 0.125f);
        } else {
            #pragma unroll
            for (int j = 0; j < 16; ++j) Qs[row][ds + j] = 0;
        }
    }

    float m_run[4], l_run[4];
    f32x4 o[4];
    #pragma unroll
    for (int r = 0; r < 4; ++r) { m_run[r] = -1e30f; l_run[r] = 0.0f; }
    #pragma unroll
    for (int n = 0; n < 4; ++n) o[n] = (f32x4){0.f, 0.f, 0.f, 0.f};

    for (int kt = 0; kt < 10; ++kt) {
        __syncthreads();
        {
            int row = tid >> 2, ds = (tid & 3) * 16;
            int key = kt * 64 + row;
            if (key < NSEQ) {
                const unsigned short* ksrc = qkv + base + (size_t)key * NQKV + 1024 + ds;
                *(ushort8*)&Ks[row][ds] = *(const ushort8*)ksrc;
                *(ushort8*)&Ks[row][ds + 8] = *(const ushort8*)(ksrc + 8);
                const unsigned short* vsrc = qkv + base + (size_t)key * NQKV + 2048 + ds;
                #pragma unroll
                for (int j = 0; j < 16; ++j) Vt[ds + j][row] = vsrc[j];
            } else {
                ushort8 z = {};
                *(ushort8*)&Ks[row][ds] = z;
                *(ushort8*)&Ks[row][ds + 8] = z;
                #pragma unroll
                for (int j = 0; j < 16; ++j) Vt[ds + j][row] = 0;
            }
        }
        __syncthreads();

        f32x4 s[4];
        #pragma unroll
        for (int n = 0; n < 4; ++n) s[n] = (f32x4){0.f, 0.f, 0.f, 0.f};
        #pragma unroll
        for (int ks = 0; ks < 2; ++ks) {
            bf16x8 qa = *(const bf16x8*)&Qs[w * 16 + lr][ks * 32 + lk];
            #pragma unroll
            for (int n = 0; n < 4; ++n) {
                bf16x8 kb = *(const bf16x8*)&Ks[n * 16 + lr][ks * 32 + lk];
                s[n] = __builtin_amdgcn_mfma_f32_16x16x32_bf16(qa, kb, s[n], 0, 0, 0);
            }
        }
        #pragma unroll
        for (int n = 0; n < 4; ++n) {
            int col = kt * 64 + n * 16 + lr;
            if (col >= NSEQ) {
                #pragma unroll
                for (int r = 0; r < 4; ++r) s[n][r] = -1e30f;
            }
        }
        float tmax[4];
        #pragma unroll
        for (int r = 0; r < 4; ++r)
            tmax[r] = fmaxf(fmaxf(s[0][r], s[1][r]), fmaxf(s[2][r], s[3][r]));
        #pragma unroll
        for (int off = 1; off < 16; off <<= 1) {
            #pragma unroll
            for (int r = 0; r < 4; ++r) tmax[r] = fmaxf(tmax[r], __shfl_xor(tmax[r], off));
        }
        float alpha[4], rs[4];
        #pragma unroll
        for (int r = 0; r < 4; ++r) {
            float mn = fmaxf(m_run[r], tmax[r]);
            alpha[r] = __expf(m_run[r] - mn);
            m_run[r] = mn;
            rs[r] = 0.0f;
        }
        #pragma unroll
        for (int n = 0; n < 4; ++n) {
            #pragma unroll
            for (int r = 0; r < 4; ++r) {
                float p = __expf(s[n][r] - m_run[r]);
                s[n][r] = p;
                rs[r] += p;
            }
        }
        #pragma unroll
        for (int off = 1; off < 16; off <<= 1) {
            #pragma unroll
            for (int r = 0; r < 4; ++r) rs[r] += __shfl_xor(rs[r], off);
        }
        #pragma unroll
        for (int r = 0; r < 4; ++r) l_run[r] = l_run[r] * alpha[r] + rs[r];
        #pragma unroll
        for (int n = 0; n < 4; ++n) {
            #pragma unroll
            for (int r = 0; r < 4; ++r) o[n][r] *= alpha[r];
        }
        #pragma unroll
        for (int n = 0; n < 4; ++n) {
            #pragma unroll
            for (int r = 0; r < 4; ++r)
                Ps[w * 16 + (l >> 4) * 4 + r][n * 16 + lr] = f2bf(s[n][r]);
        }
        __syncthreads();
        #pragma unroll
        for (int ks = 0; ks < 2; ++ks) {
            bf16x8 pa = *(const bf16x8*)&Ps[w * 16 + lr][ks * 32 + lk];
            #pragma unroll
            for (int n = 0; n < 4; ++n) {
                bf16x8 vb = *(const bf16x8*)&Vt[n * 16 + lr][ks * 32 + lk];
                o[n] = __builtin_amdgcn_mfma_f32_16x16x32_bf16(pa, vb, o[n], 0, 0, 0);
            }
        }
    }
    #pragma unroll
    for (int r = 0; r < 4; ++r) {
        int qrow = q0 + w * 16 + (l >> 4) * 4 + r;
        if (qrow < NSEQ) {
            float inv = (l_run[r] > 0.f) ? 1.0f / l_run[r] : 0.0f;
            #pragma unroll
            for (int n = 0; n < 4; ++n)
                ctx[((size_t)b * NSEQ + qrow) * EMB + h * 64 + n * 16 + lr] = f2bf(o[n][r] * inv);
        }
    }
}

extern "C" void kernel_launch(void* const* d_in, const int* in_sizes, int n_in,
                              void* d_out, int out_size, void* d_ws, size_t ws_size,
                              hipStream_t stream) {
    const float* tokens      = (const float*)d_in[0];
    const float* ln1_g       = (const float*)d_in[1];
    const float* ln1_b       = (const float*)d_in[2];
    const float* qkv_w       = (const float*)d_in[3];
    const float* qkv_b       = (const float*)d_in[4];
    const float* proj_w      = (const float*)d_in[5];
    const float* proj_b      = (const float*)d_in[6];
    const float* lora_gate_w = (const float*)d_in[7];
    const float* lora_A      = (const float*)d_in[8];
    const float* lora_B      = (const float*)d_in[9];
    const float* ln2_g       = (const float*)d_in[10];
    const float* ln2_b       = (const float*)d_in[11];
    const float* fc1_w       = (const float*)d_in[12];
    const float* fc1_b       = (const float*)d_in[13];
    const float* fc2_w       = (const float*)d_in[14];
    const float* fc2_b       = (const float*)d_in[15];
    const float* ad_gate_w   = (const float*)d_in[16];
    const float* ad_down_w   = (const float*)d_in[17];
    const float* ad_down_b   = (const float*)d_in[18];
    const float* ad_up_w     = (const float*)d_in[19];
    const float* ad_up_b     = (const float*)d_in[20];

    char* ws = (char*)d_ws;
    size_t off = 0;
    auto alloc = [&](size_t bytes) -> void* {
        void* p = ws + off;
        off += (bytes + 255) & ~(size_t)255;
        return p;
    };

    unsigned short* w_qkv  = (unsigned short*)alloc((size_t)NQKV * EMB * 2);
    unsigned short* w_proj = (unsigned short*)alloc((size_t)EMB * EMB * 2);
    unsigned short* w_fc1  = (unsigned short*)alloc((size_t)FFD * EMB * 2);
    unsigned short* w_fc2  = (unsigned short*)alloc((size_t)EMB * FFD * 2);
    unsigned short* w_acat = (unsigned short*)alloc((size_t)64 * EMB * 2);
    unsigned short* w_bcat = (unsigned short*)alloc((size_t)NQKV * 64 * 2);
    unsigned short* w_dcat = (unsigned short*)alloc((size_t)256 * EMB * 2);
    unsigned short* w_u    = (unsigned short*)alloc((size_t)EMB * 256 * 2);

    unsigned short* u1 = (unsigned short*)alloc((size_t)TOK * EMB * 2);  // normed -> mlpin
    unsigned short* u2 = (unsigned short*)alloc((size_t)TOK * EMB * 2);  // ctx
    unsigned short* u3 = (unsigned short*)alloc((size_t)TOK * FFD * 2);  // qkv -> h1
    float* tok2  = (float*)alloc((size_t)TOK * EMB * 4);
    unsigned short* hw  = (unsigned short*)alloc((size_t)TOK * 64 * 2);
    unsigned short* ahw = (unsigned short*)alloc((size_t)TOK * 256 * 2);
    float* gates = (float*)alloc((size_t)TOK * 4 * 4);
    float* ag    = (float*)alloc((size_t)TOK * 4 * 4);

    unsigned short* normed = u1;
    unsigned short* mlpin  = u1;
    unsigned short* ctx    = u2;
    unsigned short* qkv    = u3;
    unsigned short* h1     = u3;

    // ---- weight conversion / packing (3 dispatches) ----
    k_pack_all<<<2048, 256, 0, stream>>>(qkv_w, proj_w, fc1_w, fc2_w, lora_A, ad_down_w,
                                         w_qkv, w_proj, w_fc1, w_fc2, w_acat, w_dcat);
    k_pack_bcat<<<(NQKV * 64 + 255) / 256, 256, 0, stream>>>(lora_B, w_bcat);
    k_pack_u<<<(EMB * 256 + 255) / 256, 256, 0, stream>>>(ad_up_w, w_u);

    // ---- forward ----
    k_ln_gates<<<TOK, 256, 0, stream>>>(tokens, ln1_g, ln1_b, lora_gate_w, normed, gates);
    // lora down: hw = gates * (normed @ lora_A^T), bf16 out, gate group 16
    k_gemm<false, true, 16><<<73, 256, 0, stream>>>(
        normed, EMB, w_acat, EMB, EMB, TOK, 64,
        nullptr, nullptr, 0, nullptr, nullptr, gates, hw, 64, 1);
    // qkv = normed @ qkv_w^T + hw @ bcat^T + qkv_b
    k_gemm<false, true, 0><<<73 * 24, 256, 0, stream>>>(
        normed, EMB, w_qkv, EMB, EMB, TOK, NQKV,
        hw, w_bcat, 64, qkv_b, nullptr, nullptr, qkv, NQKV, 24);
    k_attn<<<dim3(256, 10), 256, 0, stream>>>(qkv, ctx);
    // tok2 = tokens + ctx @ proj^T + proj_b   (fp32)
    k_gemm<false, false, 0><<<73 * 8, 256, 0, stream>>>(
        ctx, EMB, w_proj, EMB, EMB, TOK, EMB,
        nullptr, nullptr, 0, proj_b, tokens, nullptr, tok2, EMB, 8);
    k_ln_gates<<<TOK, 256, 0, stream>>>(tok2, ln2_g, ln2_b, ad_gate_w, mlpin, ag);
    // adapter down: ahw = ag * gelu(mlpin @ d^T + db), bf16, gate group 64
    k_gemm<true, true, 64><<<73 * 2, 256, 0, stream>>>(
        mlpin, EMB, w_dcat, EMB, EMB, TOK, 256,
        nullptr, nullptr, 0, ad_down_b, nullptr, ag, ahw, 256, 2);
    // d_out = tok2 + fc2_b + ag @ ad_up_b
    k_fc2init<<<TOK, 256, 0, stream>>>(tok2, fc2_b, ag, ad_up_b, (float*)d_out);
    // h1 = gelu(mlpin @ fc1^T + fc1_b)
    k_gemm<true, true, 0><<<73 * 32, 256, 0, stream>>>(
        mlpin, EMB, w_fc1, EMB, EMB, TOK, FFD,
        nullptr, nullptr, 0, fc1_b, nullptr, nullptr, h1, FFD, 32);
    // d_out = prepped + h1 @ fc2^T + ahw @ u^T  (resid aliases Cout: each elem read-then-written by same thread)
    k_gemm<false, false, 0><<<73 * 8, 256, 0, stream>>>(
        h1, FFD, w_fc2, FFD, FFD, TOK, EMB,
        ahw, w_u, 256, nullptr, (const float*)d_out, nullptr, (float*)d_out, EMB, 8);
}

// Round 8
// 737.869 us; speedup vs baseline: 1.2285x; 1.0021x over previous
//
#include <hip/hip_runtime.h>
#include <math.h>

#define TOK 9232      // B*N = 16*577
#define EMB 1024
#define NQKV 3072
#define FFD 4096
#define NSEQ 577

typedef __bf16 bf16x8 __attribute__((ext_vector_type(8)));
typedef float f32x4 __attribute__((ext_vector_type(4)));
typedef unsigned short ushort8 __attribute__((ext_vector_type(8)));
typedef unsigned short ushort4v __attribute__((ext_vector_type(4)));

typedef __attribute__((address_space(3))) unsigned int lds_u32_t;
typedef const __attribute__((address_space(1))) unsigned int glob_u32_t;

__device__ __forceinline__ void async16(void* lds, const void* g) {
    __builtin_amdgcn_global_load_lds((glob_u32_t*)g, (lds_u32_t*)lds, 16, 0, 0);
}

__device__ __forceinline__ unsigned short f2bf(float f) {
    unsigned int u = __builtin_bit_cast(unsigned int, f);
    u = (u + 0x7fffu + ((u >> 16) & 1u)) >> 16;
    return (unsigned short)u;
}
__device__ __forceinline__ float bf2f(unsigned short s) {
    unsigned int u = ((unsigned int)s) << 16;
    return __builtin_bit_cast(float, u);
}
__device__ __forceinline__ float gelu_exact(float x) {
    return 0.5f * x * (1.0f + erff(x * 0.70710678118654752f));
}

// ---------- merged weight conversion (6 contiguous f32->bf16 segments) ----------
__global__ void k_pack_all(const float* __restrict__ s_qkv, const float* __restrict__ s_proj,
                           const float* __restrict__ s_fc1, const float* __restrict__ s_fc2,
                           const float* __restrict__ s_la,  const float* __restrict__ s_ad,
                           unsigned short* __restrict__ d_qkv, unsigned short* __restrict__ d_proj,
                           unsigned short* __restrict__ d_fc1, unsigned short* __restrict__ d_fc2,
                           unsigned short* __restrict__ d_la,  unsigned short* __restrict__ d_ad) {
    int stride = gridDim.x * 256;
    for (int i4 = blockIdx.x * 256 + threadIdx.x; i4 < 3227648; i4 += stride) {
        const float* s; unsigned short* d; int local;
        if (i4 < 786432)       { s = s_qkv;  d = d_qkv;  local = i4; }
        else if (i4 < 1048576) { s = s_proj; d = d_proj; local = i4 - 786432; }
        else if (i4 < 2097152) { s = s_fc1;  d = d_fc1;  local = i4 - 1048576; }
        else if (i4 < 3145728) { s = s_fc2;  d = d_fc2;  local = i4 - 2097152; }
        else if (i4 < 3162112) { s = s_la;   d = d_la;   local = i4 - 3145728; }
        else                   { s = s_ad;   d = d_ad;   local = i4 - 3162112; }
        float4 v = ((const float4*)s)[local];
        ushort4v o;
        o[0] = f2bf(v.x); o[1] = f2bf(v.y); o[2] = f2bf(v.z); o[3] = f2bf(v.w);
        ((ushort4v*)d)[local] = o;
    }
}
// lora_B [4][3072][16] -> Bcat[o][x*16+r]
__global__ void k_pack_bcat(const float* __restrict__ Bw, unsigned short* __restrict__ out) {
    int i = blockIdx.x * 256 + threadIdx.x;
    if (i >= 3072 * 64) return;
    int o = i >> 6, j = i & 63, x = j >> 4, r = j & 15;
    out[o * 64 + j] = f2bf(Bw[x * 3072 * 16 + o * 16 + r]);
}
// ad_up_w [4][1024][64] -> U[o][x*64+h]
__global__ void k_pack_u(const float* __restrict__ Uw, unsigned short* __restrict__ out) {
    int i = blockIdx.x * 256 + threadIdx.x;
    if (i >= 1024 * 256) return;
    int o = i >> 8, j = i & 255, x = j >> 6, h = j & 63;
    out[o * 256 + j] = f2bf(Uw[x * 65536 + o * 64 + h]);
}

// ---------- fused layernorm + 4-expert gate softmax, one block per token ----------
__global__ __launch_bounds__(256) void k_ln_gates(const float* __restrict__ x,
                                                  const float* __restrict__ g,
                                                  const float* __restrict__ b,
                                                  const float* __restrict__ gw,
                                                  unsigned short* __restrict__ out,
                                                  float* __restrict__ gates) {
    int t = blockIdx.x;
    int tid = threadIdx.x;
    const float* xp = x + (size_t)t * EMB;
    float4 v = ((const float4*)xp)[tid];
    float s = v.x + v.y + v.z + v.w;
    float sq = v.x * v.x + v.y * v.y + v.z * v.z + v.w * v.w;
    #pragma unroll
    for (int off = 32; off > 0; off >>= 1) {
        s += __shfl_down(s, off);
        sq += __shfl_down(sq, off);
    }
    __shared__ float red[8];
    if ((tid & 63) == 0) { red[tid >> 6] = s; red[(tid >> 6) + 4] = sq; }
    __syncthreads();
    float S = red[0] + red[1] + red[2] + red[3];
    float SQ = red[4] + red[5] + red[6] + red[7];
    float mean = S * (1.0f / EMB);
    float var = SQ * (1.0f / EMB) - mean * mean;
    float rstd = rsqrtf(var + 1e-6f);
    float4 gv = ((const float4*)g)[tid];
    float4 bv = ((const float4*)b)[tid];
    float n0 = (v.x - mean) * rstd * gv.x + bv.x;
    float n1 = (v.y - mean) * rstd * gv.y + bv.y;
    float n2 = (v.z - mean) * rstd * gv.z + bv.z;
    float n3 = (v.w - mean) * rstd * gv.w + bv.w;
    ushort4v o;
    o[0] = f2bf(n0); o[1] = f2bf(n1); o[2] = f2bf(n2); o[3] = f2bf(n3);
    ((ushort4v*)(out + (size_t)t * EMB))[tid] = o;
    float p[4];
    #pragma unroll
    for (int xx = 0; xx < 4; ++xx) {
        float4 gr = ((const float4*)(gw + xx * EMB))[tid];
        p[xx] = n0 * gr.x + n1 * gr.y + n2 * gr.z + n3 * gr.w;
    }
    #pragma unroll
    for (int off = 32; off > 0; off >>= 1) {
        #pragma unroll
        for (int xx = 0; xx < 4; ++xx) p[xx] += __shfl_down(p[xx], off);
    }
    __shared__ float red2[4][4];
    if ((tid & 63) == 0) {
        #pragma unroll
        for (int xx = 0; xx < 4; ++xx) red2[tid >> 6][xx] = p[xx];
    }
    __syncthreads();
    if (tid == 0) {
        float l[4];
        #pragma unroll
        for (int xx = 0; xx < 4; ++xx) l[xx] = red2[0][xx] + red2[1][xx] + red2[2][xx] + red2[3][xx];
        float m = fmaxf(fmaxf(l[0], l[1]), fmaxf(l[2], l[3]));
        float e[4], ssum = 0.f;
        #pragma unroll
        for (int xx = 0; xx < 4; ++xx) { e[xx] = expf(l[xx] - m); ssum += e[xx]; }
        float inv = 1.0f / ssum;
        #pragma unroll
        for (int xx = 0; xx < 4; ++xx) gates[t * 4 + xx] = e[xx] * inv;
    }
}

// d_out[t][o] = tok2[t][o] + fc2_b[o] + sum_x ag[t][x] * ad_up_b[x][o]
__global__ __launch_bounds__(256) void k_fc2init(const float* __restrict__ tok2,
                                                 const float* __restrict__ fc2b,
                                                 const float* __restrict__ ag,
                                                 const float* __restrict__ upb,
                                                 float* __restrict__ out) {
    int t = blockIdx.x;
    int tid = threadIdx.x;
    float g0 = ag[t * 4 + 0], g1 = ag[t * 4 + 1], g2 = ag[t * 4 + 2], g3 = ag[t * 4 + 3];
    float4 b0 = ((const float4*)(upb + 0 * EMB))[tid];
    float4 b1 = ((const float4*)(upb + 1 * EMB))[tid];
    float4 b2 = ((const float4*)(upb + 2 * EMB))[tid];
    float4 b3 = ((const float4*)(upb + 3 * EMB))[tid];
    float4 fb = ((const float4*)fc2b)[tid];
    float4 r = ((const float4*)(tok2 + (size_t)t * EMB))[tid];
    r.x += fb.x + g0 * b0.x + g1 * b1.x + g2 * b2.x + g3 * b3.x;
    r.y += fb.y + g0 * b0.y + g1 * b1.y + g2 * b2.y + g3 * b3.y;
    r.z += fb.z + g0 * b0.z + g1 * b1.z + g2 * b2.z + g3 * b3.z;
    r.w += fb.w + g0 * b0.w + g1 * b1.w + g2 * b2.w + g3 * b3.w;
    ((float4*)(out + (size_t)t * EMB))[tid] = r;
}

// ---------- MFMA GEMM: 128x128 tile, BK=32, 3-buffer LDS ring, counted vmcnt(8),
// T2 XOR swizzle (16B slots): phys slot p of row r holds global slot p ^ ((r>>1)&3).
// Stage: source slot = (l&3) ^ ((l>>3)&3)  [row bits 1-2 = bits 1-2 of l>>2]
// Read:  phys slot  = (l>>4) ^ ((lr>>1)&3) -> 2-way max (free), 8-cycle floor.
#define VMCNT8 asm volatile("s_waitcnt vmcnt(8)" ::: "memory")
#define BAR __builtin_amdgcn_s_barrier()

template<bool GELU, bool BF16OUT, int GG>
__global__ __launch_bounds__(256) void k_gemm(
    const unsigned short* __restrict__ A, int lda,
    const unsigned short* __restrict__ W, int ldw, int K1,
    int M, int N,
    const unsigned short* __restrict__ A2, const unsigned short* __restrict__ W2, int K2,
    const float* __restrict__ bias, const float* __restrict__ resid,
    const float* __restrict__ aux,
    void* __restrict__ Cout, int ldc, int gy)
{
    __shared__ unsigned short As[3][128][32];
    __shared__ unsigned short Ws[3][128][32];
    int tid = threadIdx.x;
    int nwg = gridDim.x, orig = blockIdx.x;
    int xcd = orig & 7, lid = orig >> 3;
    int q = nwg >> 3, r = nwg & 7;
    int wg = (xcd < r ? xcd * (q + 1) : r * (q + 1) + (xcd - r) * q) + lid;
    int bm128 = (wg / gy) * 128;
    int bn128 = (wg % gy) * 128;

    int l = tid & 63, w = tid >> 6;
    int wr = w >> 1, wc = w & 1;
    int lr = l & 15;
    int srow = l >> 2;
    int sslot = (((l & 3) ^ ((l >> 3) & 3)) << 3);   // inverse-swizzled source slot (elems)

    int KT1 = K1 >> 5, KT2 = K2 >> 5;
    int KT = KT1 + KT2;

    // per-thread staging source pointers (rows clamped; garbage feeds only dead rows/cols)
    int ra0 = bm128 + w * 32 + srow;      if (ra0 > M - 1) ra0 = M - 1;
    int ra1 = bm128 + w * 32 + 16 + srow; if (ra1 > M - 1) ra1 = M - 1;
    int rb0 = bn128 + w * 32 + srow;      if (rb0 > N - 1) rb0 = N - 1;
    int rb1 = bn128 + w * 32 + 16 + srow; if (rb1 > N - 1) rb1 = N - 1;
    const unsigned short* pA0 = A + (size_t)ra0 * lda + sslot;
    const unsigned short* pA1 = A + (size_t)ra1 * lda + sslot;
    const unsigned short* pB0 = W + (size_t)rb0 * ldw + sslot;
    const unsigned short* pB1 = W + (size_t)rb1 * ldw + sslot;
    const unsigned short* A2s = A2 ? A2 : A;
    const unsigned short* W2s = W2 ? W2 : W;
    int K2s = A2 ? K2 : lda;
    const unsigned short* qA0 = A2s + (size_t)ra0 * K2s + sslot;
    const unsigned short* qA1 = A2s + (size_t)ra1 * K2s + sslot;
    const unsigned short* qB0 = W2s + (size_t)rb0 * K2s + sslot;
    const unsigned short* qB1 = W2s + (size_t)rb1 * K2s + sslot;

    // swizzled, loop-invariant ds_read byte offsets
    int ksl = l >> 4;                      // global K-slot this lane needs
    int psl = (ksl ^ ((lr >> 1) & 3)) << 4;  // physical 16B slot byte offset
    int offA[4], offB[4];
    #pragma unroll
    for (int m = 0; m < 4; ++m) offA[m] = ((wr * 64 + m * 16 + lr) << 6) + psl;
    #pragma unroll
    for (int n = 0; n < 4; ++n) offB[n] = ((wc * 64 + n * 16 + lr) << 6) + psl;

    f32x4 acc[4][4];
    #pragma unroll
    for (int m = 0; m < 4; ++m)
        #pragma unroll
        for (int n = 0; n < 4; ++n) acc[m][n] = (f32x4){0.f, 0.f, 0.f, 0.f};

#define STAGE(s_, sb_) do {                                          \
    char* da_ = (char*)As + (sb_) * 8192 + w * 2048;                 \
    char* db_ = (char*)Ws + (sb_) * 8192 + w * 2048;                 \
    int ss_ = (s_);                                                  \
    if (ss_ < KT1) {                                                 \
        int ko_ = ss_ << 5;                                          \
        async16(da_,        pA0 + ko_);                              \
        async16(da_ + 1024, pA1 + ko_);                              \
        async16(db_,        pB0 + ko_);                              \
        async16(db_ + 1024, pB1 + ko_);                              \
    } else {                                                         \
        int ko_ = (ss_ - KT1) << 5;                                  \
        async16(da_,        qA0 + ko_);                              \
        async16(da_ + 1024, qA1 + ko_);                              \
        async16(db_,        qB0 + ko_);                              \
        async16(db_ + 1024, qB1 + ko_);                              \
    }                                                                \
} while (0)

    STAGE(0, 0);
    STAGE(1, 1);

    int cb = 0, sb = 2;
    #pragma unroll 1
    for (int t = 0; t < KT; ++t) {
        int s = t + 2; if (s >= KT) s = 0;   // wrap re-stage: buffer never read
        STAGE(s, sb);
        VMCNT8;   // tiles t+1,t+2 (8 loads) stay in flight; tile t complete
        BAR;
        const char* baseA = (const char*)As + cb * 8192;
        const char* baseB = (const char*)Ws + cb * 8192;
        bf16x8 af[4], bfr[4];
        #pragma unroll
        for (int m = 0; m < 4; ++m) af[m] = *(const bf16x8*)(baseA + offA[m]);
        #pragma unroll
        for (int n = 0; n < 4; ++n) bfr[n] = *(const bf16x8*)(baseB + offB[n]);
        __builtin_amdgcn_s_setprio(1);
        #pragma unroll
        for (int m = 0; m < 4; ++m)
            #pragma unroll
            for (int n = 0; n < 4; ++n)
                acc[m][n] = __builtin_amdgcn_mfma_f32_16x16x32_bf16(af[m], bfr[n], acc[m][n], 0, 0, 0);
        __builtin_amdgcn_s_setprio(0);
        BAR;      // all waves done reading buf cb before it is re-staged (2 iters later)
        cb = (cb == 2) ? 0 : cb + 1;
        sb = (sb == 2) ? 0 : sb + 1;
    }
#undef STAGE

    int rbase = bm128 + wr * 64;
    int cbase = bn128 + wc * 64;
    #pragma unroll
    for (int n = 0; n < 4; ++n) {
        int col = cbase + n * 16 + lr;
        if (col >= N) continue;
        float bv = bias ? bias[col] : 0.0f;
        #pragma unroll
        for (int m = 0; m < 4; ++m) {
            #pragma unroll
            for (int rr = 0; rr < 4; ++rr) {
                int row = rbase + m * 16 + (l >> 4) * 4 + rr;
                if (row >= M) continue;
                float c = acc[m][n][rr] + bv;
                if (GELU) c = gelu_exact(c);
                if (GG > 0) c *= aux[row * 4 + col / (GG > 0 ? GG : 1)];
                if (resid) c += resid[(size_t)row * ldc + col];
                if (BF16OUT) ((unsigned short*)Cout)[(size_t)row * ldc + col] = f2bf(c);
                else ((float*)Cout)[(size_t)row * ldc + col] = c;
            }
        }
    }
}

// ---------- flash attention: one block per (b*h, 64-row q tile) ----------
__global__ __launch_bounds__(256) void k_attn(const unsigned short* __restrict__ qkv,
                                              unsigned short* __restrict__ ctx) {
    int bh = blockIdx.x;
    int qt = blockIdx.y;
    int b = bh >> 4, h = bh & 15;
    int tid = threadIdx.x;
    int l = tid & 63;
    int w = tid >> 6;
    int lr = l & 15;
    int lk = (l >> 4) * 8;

    __shared__ unsigned short Qs[64][72];
    __shared__ unsigned short Ks[64][72];
    __shared__ unsigned short Vt[64][72];
    __shared__ unsigned short Ps[64][72];

    const size_t base = (size_t)b * NSEQ * NQKV + (size_t)h * 64;
    int q0 = qt * 64;

    {
        int row = tid >> 2, ds = (tid & 3) * 16;
        int qrow = q0 + row;
        if (qrow < NSEQ) {
            const unsigned short* src = qkv + base + (size_t)qrow * NQKV + ds;
            #pragma unroll
            for (int j = 0; j < 16; ++j) Qs[row][ds + j] = f2bf(bf2f(src[j]) * 0.125f);
        } else {
            #pragma unroll
            for (int j = 0; j < 16; ++j) Qs[row][ds + j] = 0;
        }
    }

    float m_run[4], l_run[4];
    f32x4 o[4];
    #pragma unroll
    for (int r = 0; r < 4; ++r) { m_run[r] = -1e30f; l_run[r] = 0.0f; }
    #pragma unroll
    for (int n = 0; n < 4; ++n) o[n] = (f32x4){0.f, 0.f, 0.f, 0.f};

    for (int kt = 0; kt < 10; ++kt) {
        __syncthreads();
        {
            int row = tid >> 2, ds = (tid & 3) * 16;
            int key = kt * 64 + row;
            if (key < NSEQ) {
                const unsigned short* ksrc = qkv + base + (size_t)key * NQKV + 1024 + ds;
                *(ushort8*)&Ks[row][ds] = *(const ushort8*)ksrc;
                *(ushort8*)&Ks[row][ds + 8] = *(const ushort8*)(ksrc + 8);
                const unsigned short* vsrc = qkv + base + (size_t)key * NQKV + 2048 + ds;
                #pragma unroll
                for (int j = 0; j < 16; ++j) Vt[ds + j][row] = vsrc[j];
            } else {
                ushort8 z = {};
                *(ushort8*)&Ks[row][ds] = z;
                *(ushort8*)&Ks[row][ds + 8] = z;
                #pragma unroll
                for (int j = 0; j < 16; ++j) Vt[ds + j][row] = 0;
            }
        }
        __syncthreads();

        f32x4 s[4];
        #pragma unroll
        for (int n = 0; n < 4; ++n) s[n] = (f32x4){0.f, 0.f, 0.f, 0.f};
        #pragma unroll
        for (int ks = 0; ks < 2; ++ks) {
            bf16x8 qa = *(const bf16x8*)&Qs[w * 16 + lr][ks * 32 + lk];
            #pragma unroll
            for (int n = 0; n < 4; ++n) {
                bf16x8 kb = *(const bf16x8*)&Ks[n * 16 + lr][ks * 32 + lk];
                s[n] = __builtin_amdgcn_mfma_f32_16x16x32_bf16(qa, kb, s[n], 0, 0, 0);
            }
        }
        #pragma unroll
        for (int n = 0; n < 4; ++n) {
            int col = kt * 64 + n * 16 + lr;
            if (col >= NSEQ) {
                #pragma unroll
                for (int r = 0; r < 4; ++r) s[n][r] = -1e30f;
            }
        }
        float tmax[4];
        #pragma unroll
        for (int r = 0; r < 4; ++r)
            tmax[r] = fmaxf(fmaxf(s[0][r], s[1][r]), fmaxf(s[2][r], s[3][r]));
        #pragma unroll
        for (int off = 1; off < 16; off <<= 1) {
            #pragma unroll
            for (int r = 0; r < 4; ++r) tmax[r] = fmaxf(tmax[r], __shfl_xor(tmax[r], off));
        }
        float alpha[4], rs[4];
        #pragma unroll
        for (int r = 0; r < 4; ++r) {
            float mn = fmaxf(m_run[r], tmax[r]);
            alpha[r] = __expf(m_run[r] - mn);
            m_run[r] = mn;
            rs[r] = 0.0f;
        }
        #pragma unroll
        for (int n = 0; n < 4; ++n) {
            #pragma unroll
            for (int r = 0; r < 4; ++r) {
                float p = __expf(s[n][r] - m_run[r]);
                s[n][r] = p;
                rs[r] += p;
            }
        }
        #pragma unroll
        for (int off = 1; off < 16; off <<= 1) {
            #pragma unroll
            for (int r = 0; r < 4; ++r) rs[r] += __shfl_xor(rs[r], off);
        }
        #pragma unroll
        for (int r = 0; r < 4; ++r) l_run[r] = l_run[r] * alpha[r] + rs[r];
        #pragma unroll
        for (int n = 0; n < 4; ++n) {
            #pragma unroll
            for (int r = 0; r < 4; ++r) o[n][r] *= alpha[r];
        }
        #pragma unroll
        for (int n = 0; n < 4; ++n) {
            #pragma unroll
            for (int r = 0; r < 4; ++r)
                Ps[w * 16 + (l >> 4) * 4 + r][n * 16 + lr] = f2bf(s[n][r]);
        }
        __syncthreads();
        #pragma unroll
        for (int ks = 0; ks < 2; ++ks) {
            bf16x8 pa = *(const bf16x8*)&Ps[w * 16 + lr][ks * 32 + lk];
            #pragma unroll
            for (int n = 0; n < 4; ++n) {
                bf16x8 vb = *(const bf16x8*)&Vt[n * 16 + lr][ks * 32 + lk];
                o[n] = __builtin_amdgcn_mfma_f32_16x16x32_bf16(pa, vb, o[n], 0, 0, 0);
            }
        }
    }
    #pragma unroll
    for (int r = 0; r < 4; ++r) {
        int qrow = q0 + w * 16 + (l >> 4) * 4 + r;
        if (qrow < NSEQ) {
            float inv = (l_run[r] > 0.f) ? 1.0f / l_run[r] : 0.0f;
            #pragma unroll
            for (int n = 0; n < 4; ++n)
                ctx[((size_t)b * NSEQ + qrow) * EMB + h * 64 + n * 16 + lr] = f2bf(o[n][r] * inv);
        }
    }
}

extern "C" void kernel_launch(void* const* d_in, const int* in_sizes, int n_in,
                              void* d_out, int out_size, void* d_ws, size_t ws_size,
                              hipStream_t stream) {
    const float* tokens      = (const float*)d_in[0];
    const float* ln1_g       = (const float*)d_in[1];
    const float* ln1_b       = (const float*)d_in[2];
    const float* qkv_w       = (const float*)d_in[3];
    const float* qkv_b       = (const float*)d_in[4];
    const float* proj_w      = (const float*)d_in[5];
    const float* proj_b      = (const float*)d_in[6];
    const float* lora_gate_w = (const float*)d_in[7];
    const float* lora_A      = (const float*)d_in[8];
    const float* lora_B      = (const float*)d_in[9];
    const float* ln2_g       = (const float*)d_in[10];
    const float* ln2_b       = (const float*)d_in[11];
    const float* fc1_w       = (const float*)d_in[12];
    const float* fc1_b       = (const float*)d_in[13];
    const float* fc2_w       = (const float*)d_in[14];
    const float* fc2_b       = (const float*)d_in[15];
    const float* ad_gate_w   = (const float*)d_in[16];
    const float* ad_down_w   = (const float*)d_in[17];
    const float* ad_down_b   = (const float*)d_in[18];
    const float* ad_up_w     = (const float*)d_in[19];
    const float* ad_up_b     = (const float*)d_in[20];

    char* ws = (char*)d_ws;
    size_t off = 0;
    auto alloc = [&](size_t bytes) -> void* {
        void* p = ws + off;
        off += (bytes + 255) & ~(size_t)255;
        return p;
    };

    unsigned short* w_qkv  = (unsigned short*)alloc((size_t)NQKV * EMB * 2);
    unsigned short* w_proj = (unsigned short*)alloc((size_t)EMB * EMB * 2);
    unsigned short* w_fc1  = (unsigned short*)alloc((size_t)FFD * EMB * 2);
    unsigned short* w_fc2  = (unsigned short*)alloc((size_t)EMB * FFD * 2);
    unsigned short* w_acat = (unsigned short*)alloc((size_t)64 * EMB * 2);
    unsigned short* w_bcat = (unsigned short*)alloc((size_t)NQKV * 64 * 2);
    unsigned short* w_dcat = (unsigned short*)alloc((size_t)256 * EMB * 2);
    unsigned short* w_u    = (unsigned short*)alloc((size_t)EMB * 256 * 2);

    unsigned short* u1 = (unsigned short*)alloc((size_t)TOK * EMB * 2);  // normed -> mlpin
    unsigned short* u2 = (unsigned short*)alloc((size_t)TOK * EMB * 2);  // ctx
    unsigned short* u3 = (unsigned short*)alloc((size_t)TOK * FFD * 2);  // qkv -> h1
    float* tok2  = (float*)alloc((size_t)TOK * EMB * 4);
    unsigned short* hw  = (unsigned short*)alloc((size_t)TOK * 64 * 2);
    unsigned short* ahw = (unsigned short*)alloc((size_t)TOK * 256 * 2);
    float* gates = (float*)alloc((size_t)TOK * 4 * 4);
    float* ag    = (float*)alloc((size_t)TOK * 4 * 4);

    unsigned short* normed = u1;
    unsigned short* mlpin  = u1;
    unsigned short* ctx    = u2;
    unsigned short* qkv    = u3;
    unsigned short* h1     = u3;

    // ---- weight conversion / packing (3 dispatches) ----
    k_pack_all<<<2048, 256, 0, stream>>>(qkv_w, proj_w, fc1_w, fc2_w, lora_A, ad_down_w,
                                         w_qkv, w_proj, w_fc1, w_fc2, w_acat, w_dcat);
    k_pack_bcat<<<(NQKV * 64 + 255) / 256, 256, 0, stream>>>(lora_B, w_bcat);
    k_pack_u<<<(EMB * 256 + 255) / 256, 256, 0, stream>>>(ad_up_w, w_u);

    // ---- forward ----
    k_ln_gates<<<TOK, 256, 0, stream>>>(tokens, ln1_g, ln1_b, lora_gate_w, normed, gates);
    // lora down: hw = gates * (normed @ lora_A^T), bf16 out, gate group 16
    k_gemm<false, true, 16><<<73, 256, 0, stream>>>(
        normed, EMB, w_acat, EMB, EMB, TOK, 64,
        nullptr, nullptr, 0, nullptr, nullptr, gates, hw, 64, 1);
    // qkv = normed @ qkv_w^T + hw @ bcat^T + qkv_b
    k_gemm<false, true, 0><<<73 * 24, 256, 0, stream>>>(
        normed, EMB, w_qkv, EMB, EMB, TOK, NQKV,
        hw, w_bcat, 64, qkv_b, nullptr, nullptr, qkv, NQKV, 24);
    k_attn<<<dim3(256, 10), 256, 0, stream>>>(qkv, ctx);
    // tok2 = tokens + ctx @ proj^T + proj_b   (fp32)
    k_gemm<false, false, 0><<<73 * 8, 256, 0, stream>>>(
        ctx, EMB, w_proj, EMB, EMB, TOK, EMB,
        nullptr, nullptr, 0, proj_b, tokens, nullptr, tok2, EMB, 8);
    k_ln_gates<<<TOK, 256, 0, stream>>>(tok2, ln2_g, ln2_b, ad_gate_w, mlpin, ag);
    // adapter down: ahw = ag * gelu(mlpin @ d^T + db), bf16, gate group 64
    k_gemm<true, true, 64><<<73 * 2, 256, 0, stream>>>(
        mlpin, EMB, w_dcat, EMB, EMB, TOK, 256,
        nullptr, nullptr, 0, ad_down_b, nullptr, ag, ahw, 256, 2);
    // d_out = tok2 + fc2_b + ag @ ad_up_b
    k_fc2init<<<TOK, 256, 0, stream>>>(tok2, fc2_b, ag, ad_up_b, (float*)d_out);
    // h1 = gelu(mlpin @ fc1^T + fc1_b)
    k_gemm<true, true, 0><<<73 * 32, 256, 0, stream>>>(
        mlpin, EMB, w_fc1, EMB, EMB, TOK, FFD,
        nullptr, nullptr, 0, fc1_b, nullptr, nullptr, h1, FFD, 32);
    // d_out = prepped + h1 @ fc2^T + ahw @ u^T  (resid aliases Cout: each elem read-then-written by same thread)
    k_gemm<false, false, 0><<<73 * 8, 256, 0, stream>>>(
        h1, FFD, w_fc2, FFD, FFD, TOK, EMB,
        ahw, w_u, 256, nullptr, (const float*)d_out, nullptr, (float*)d_out, EMB, 8);
}

// Round 10
// 721.591 us; speedup vs baseline: 1.2563x; 1.0226x over previous
//
#include <hip/hip_runtime.h>
#include <math.h>

#define TOK 9232      // B*N = 16*577
#define EMB 1024
#define NQKV 3072
#define FFD 4096
#define NSEQ 577

typedef __bf16 bf16x8 __attribute__((ext_vector_type(8)));
typedef float f32x4 __attribute__((ext_vector_type(4)));
typedef unsigned short ushort8 __attribute__((ext_vector_type(8)));
typedef unsigned short ushort4v __attribute__((ext_vector_type(4)));

typedef __attribute__((address_space(3))) unsigned int lds_u32_t;
typedef const __attribute__((address_space(1))) unsigned int glob_u32_t;

__device__ __forceinline__ void async16(void* lds, const void* g) {
    __builtin_amdgcn_global_load_lds((glob_u32_t*)g, (lds_u32_t*)lds, 16, 0, 0);
}

__device__ __forceinline__ unsigned short f2bf(float f) {
    unsigned int u = __builtin_bit_cast(unsigned int, f);
    u = (u + 0x7fffu + ((u >> 16) & 1u)) >> 16;
    return (unsigned short)u;
}
__device__ __forceinline__ float bf2f(unsigned short s) {
    unsigned int u = ((unsigned int)s) << 16;
    return __builtin_bit_cast(float, u);
}
__device__ __forceinline__ float gelu_exact(float x) {
    return 0.5f * x * (1.0f + erff(x * 0.70710678118654752f));
}

// ---------- merged weight conversion (6 contiguous f32->bf16 segments) ----------
__global__ void k_pack_all(const float* __restrict__ s_qkv, const float* __restrict__ s_proj,
                           const float* __restrict__ s_fc1, const float* __restrict__ s_fc2,
                           const float* __restrict__ s_la,  const float* __restrict__ s_ad,
                           unsigned short* __restrict__ d_qkv, unsigned short* __restrict__ d_proj,
                           unsigned short* __restrict__ d_fc1, unsigned short* __restrict__ d_fc2,
                           unsigned short* __restrict__ d_la,  unsigned short* __restrict__ d_ad) {
    int stride = gridDim.x * 256;
    for (int i4 = blockIdx.x * 256 + threadIdx.x; i4 < 3227648; i4 += stride) {
        const float* s; unsigned short* d; int local;
        if (i4 < 786432)       { s = s_qkv;  d = d_qkv;  local = i4; }
        else if (i4 < 1048576) { s = s_proj; d = d_proj; local = i4 - 786432; }
        else if (i4 < 2097152) { s = s_fc1;  d = d_fc1;  local = i4 - 1048576; }
        else if (i4 < 3145728) { s = s_fc2;  d = d_fc2;  local = i4 - 2097152; }
        else if (i4 < 3162112) { s = s_la;   d = d_la;   local = i4 - 3145728; }
        else                   { s = s_ad;   d = d_ad;   local = i4 - 3162112; }
        float4 v = ((const float4*)s)[local];
        ushort4v o;
        o[0] = f2bf(v.x); o[1] = f2bf(v.y); o[2] = f2bf(v.z); o[3] = f2bf(v.w);
        ((ushort4v*)d)[local] = o;
    }
}
// lora_B [4][3072][16] -> Bcat[o][x*16+r]
__global__ void k_pack_bcat(const float* __restrict__ Bw, unsigned short* __restrict__ out) {
    int i = blockIdx.x * 256 + threadIdx.x;
    if (i >= 3072 * 64) return;
    int o = i >> 6, j = i & 63, x = j >> 4, r = j & 15;
    out[o * 64 + j] = f2bf(Bw[x * 3072 * 16 + o * 16 + r]);
}
// ad_up_w [4][1024][64] -> U[o][x*64+h]
__global__ void k_pack_u(const float* __restrict__ Uw, unsigned short* __restrict__ out) {
    int i = blockIdx.x * 256 + threadIdx.x;
    if (i >= 1024 * 256) return;
    int o = i >> 8, j = i & 255, x = j >> 6, h = j & 63;
    out[o * 256 + j] = f2bf(Uw[x * 65536 + o * 64 + h]);
}

// ---------- fused layernorm + 4-expert gate softmax, one block per token ----------
__global__ __launch_bounds__(256) void k_ln_gates(const float* __restrict__ x,
                                                  const float* __restrict__ g,
                                                  const float* __restrict__ b,
                                                  const float* __restrict__ gw,
                                                  unsigned short* __restrict__ out,
                                                  float* __restrict__ gates) {
    int t = blockIdx.x;
    int tid = threadIdx.x;
    const float* xp = x + (size_t)t * EMB;
    float4 v = ((const float4*)xp)[tid];
    float s = v.x + v.y + v.z + v.w;
    float sq = v.x * v.x + v.y * v.y + v.z * v.z + v.w * v.w;
    #pragma unroll
    for (int off = 32; off > 0; off >>= 1) {
        s += __shfl_down(s, off);
        sq += __shfl_down(sq, off);
    }
    __shared__ float red[8];
    if ((tid & 63) == 0) { red[tid >> 6] = s; red[(tid >> 6) + 4] = sq; }
    __syncthreads();
    float S = red[0] + red[1] + red[2] + red[3];
    float SQ = red[4] + red[5] + red[6] + red[7];
    float mean = S * (1.0f / EMB);
    float var = SQ * (1.0f / EMB) - mean * mean;
    float rstd = rsqrtf(var + 1e-6f);
    float4 gv = ((const float4*)g)[tid];
    float4 bv = ((const float4*)b)[tid];
    float n0 = (v.x - mean) * rstd * gv.x + bv.x;
    float n1 = (v.y - mean) * rstd * gv.y + bv.y;
    float n2 = (v.z - mean) * rstd * gv.z + bv.z;
    float n3 = (v.w - mean) * rstd * gv.w + bv.w;
    ushort4v o;
    o[0] = f2bf(n0); o[1] = f2bf(n1); o[2] = f2bf(n2); o[3] = f2bf(n3);
    ((ushort4v*)(out + (size_t)t * EMB))[tid] = o;
    float p[4];
    #pragma unroll
    for (int xx = 0; xx < 4; ++xx) {
        float4 gr = ((const float4*)(gw + xx * EMB))[tid];
        p[xx] = n0 * gr.x + n1 * gr.y + n2 * gr.z + n3 * gr.w;
    }
    #pragma unroll
    for (int off = 32; off > 0; off >>= 1) {
        #pragma unroll
        for (int xx = 0; xx < 4; ++xx) p[xx] += __shfl_down(p[xx], off);
    }
    __shared__ float red2[4][4];
    if ((tid & 63) == 0) {
        #pragma unroll
        for (int xx = 0; xx < 4; ++xx) red2[tid >> 6][xx] = p[xx];
    }
    __syncthreads();
    if (tid == 0) {
        float l[4];
        #pragma unroll
        for (int xx = 0; xx < 4; ++xx) l[xx] = red2[0][xx] + red2[1][xx] + red2[2][xx] + red2[3][xx];
        float m = fmaxf(fmaxf(l[0], l[1]), fmaxf(l[2], l[3]));
        float e[4], ssum = 0.f;
        #pragma unroll
        for (int xx = 0; xx < 4; ++xx) { e[xx] = expf(l[xx] - m); ssum += e[xx]; }
        float inv = 1.0f / ssum;
        #pragma unroll
        for (int xx = 0; xx < 4; ++xx) gates[t * 4 + xx] = e[xx] * inv;
    }
}

// d_out[t][o] = tok2[t][o] + fc2_b[o] + sum_x ag[t][x] * ad_up_b[x][o]
__global__ __launch_bounds__(256) void k_fc2init(const float* __restrict__ tok2,
                                                 const float* __restrict__ fc2b,
                                                 const float* __restrict__ ag,
                                                 const float* __restrict__ upb,
                                                 float* __restrict__ out) {
    int t = blockIdx.x;
    int tid = threadIdx.x;
    float g0 = ag[t * 4 + 0], g1 = ag[t * 4 + 1], g2 = ag[t * 4 + 2], g3 = ag[t * 4 + 3];
    float4 b0 = ((const float4*)(upb + 0 * EMB))[tid];
    float4 b1 = ((const float4*)(upb + 1 * EMB))[tid];
    float4 b2 = ((const float4*)(upb + 2 * EMB))[tid];
    float4 b3 = ((const float4*)(upb + 3 * EMB))[tid];
    float4 fb = ((const float4*)fc2b)[tid];
    float4 r = ((const float4*)(tok2 + (size_t)t * EMB))[tid];
    r.x += fb.x + g0 * b0.x + g1 * b1.x + g2 * b2.x + g3 * b3.x;
    r.y += fb.y + g0 * b0.y + g1 * b1.y + g2 * b2.y + g3 * b3.y;
    r.z += fb.z + g0 * b0.z + g1 * b1.z + g2 * b2.z + g3 * b3.z;
    r.w += fb.w + g0 * b0.w + g1 * b1.w + g2 * b2.w + g3 * b3.w;
    ((float4*)(out + (size_t)t * EMB))[tid] = r;
}

// ---------- MFMA GEMM: (MF*32)x128 tile, BK=32, 3-buffer LDS ring,
// single-barrier pipeline: vmcnt(CPW) -> s_barrier -> ds_read(buf t) + stage(t+2) -> MFMA.
// RAW: vmcnt before barrier => every wave's stage(t) landed when any wave reads.
// WAR: barrier arrival implies iter t-1 reads consumed => stage(t+2) into buf (t-1)%3 safe.
// T2 XOR swizzle (16B slots within 64B rows): conflict-free, verified R8 (conflicts=0).
#define BAR __builtin_amdgcn_s_barrier()

template<bool GELU, bool BF16OUT, int GG, int MF>
__global__ __launch_bounds__(256) void k_gemm(
    const unsigned short* __restrict__ A, int lda,
    const unsigned short* __restrict__ W, int ldw, int K1,
    int M, int N,
    const unsigned short* __restrict__ A2, const unsigned short* __restrict__ W2, int K2,
    const float* __restrict__ bias, const float* __restrict__ resid,
    const float* __restrict__ aux,
    void* __restrict__ Cout, int ldc, int gy)
{
    constexpr int CA = MF * 2;            // A chunks (16 rows x 32 cols = 1KB each)
    constexpr int CPW = (CA + 8) / 4;     // chunks staged per wave (= per-thread loads/stage)
    constexpr int BUFB = (CA + 8) * 1024; // ring buffer bytes (A region then B region)
    __shared__ __attribute__((aligned(16))) char Sbuf[3 * BUFB];

    int tid = threadIdx.x;
    int nwg = gridDim.x, orig = blockIdx.x;
    int xcd = orig & 7, lid = orig >> 3;
    int q = nwg >> 3, r = nwg & 7;
    int wg = (xcd < r ? xcd * (q + 1) : r * (q + 1) + (xcd - r) * q) + lid;
    int bm = (wg / gy) * (MF * 32);
    int bn = (wg % gy) * 128;

    int l = tid & 63, w = tid >> 6;
    int wr = w >> 1, wc = w & 1;
    int lr = l & 15;
    int sslot = (((l & 3) ^ ((l >> 3) & 3)) << 3);   // inverse-swizzled source slot (elems)

    int KT1 = K1 >> 5, KT2 = K2 >> 5;
    int KT = KT1 + KT2;

    const unsigned short* A2s = A2 ? A2 : A;
    const unsigned short* W2s = W2 ? W2 : W;
    int K2s = A2 ? K2 : lda;

    // per-thread staging sources (rows clamped: garbage feeds only dead rows/cols)
    const unsigned short* sp1[CPW];
    const unsigned short* sp2[CPW];
    int ldsu[CPW];                        // wave-uniform LDS chunk base offsets
    #pragma unroll
    for (int j = 0; j < CPW; ++j) {
        int c = w * CPW + j;
        ldsu[j] = c << 10;
        if (c < CA) {
            int rw = bm + c * 16 + (l >> 2); if (rw > M - 1) rw = M - 1;
            sp1[j] = A + (size_t)rw * lda + sslot;
            sp2[j] = A2s + (size_t)rw * K2s + sslot;
        } else {
            int rw = bn + (c - CA) * 16 + (l >> 2); if (rw > N - 1) rw = N - 1;
            sp1[j] = W + (size_t)rw * ldw + sslot;
            sp2[j] = W2s + (size_t)rw * K2s + sslot;
        }
    }

    // swizzled, loop-invariant ds_read byte offsets
    int psl = ((l >> 4) ^ ((lr >> 1) & 3)) << 4;
    int offA[MF], offB[4];
    #pragma unroll
    for (int m = 0; m < MF; ++m) offA[m] = ((wr * (MF * 16) + m * 16 + lr) << 6) + psl;
    #pragma unroll
    for (int n = 0; n < 4; ++n) offB[n] = (CA << 10) + ((wc * 64 + n * 16 + lr) << 6) + psl;

    f32x4 acc[MF][4];
    #pragma unroll
    for (int m = 0; m < MF; ++m)
        #pragma unroll
        for (int n = 0; n < 4; ++n) acc[m][n] = (f32x4){0.f, 0.f, 0.f, 0.f};

    auto stage = [&](int ss, int sb_) {
        char* db = Sbuf + sb_ * BUFB;
        if (ss < KT1) {
            int ko = ss << 5;
            #pragma unroll
            for (int j = 0; j < CPW; ++j) async16(db + ldsu[j], sp1[j] + ko);
        } else {
            int ko = (ss - KT1) << 5;
            #pragma unroll
            for (int j = 0; j < CPW; ++j) async16(db + ldsu[j], sp2[j] + ko);
        }
    };

    stage(0, 0);
    stage(1, 1);

    int cb = 0, sb = 2;
    #pragma unroll 1
    for (int t = 0; t < KT; ++t) {
        // drain MY stage(t) (leave stage(t+1)'s CPW loads in flight)
        if constexpr (CPW == 4) asm volatile("s_waitcnt vmcnt(4)" ::: "memory");
        else                    asm volatile("s_waitcnt vmcnt(3)" ::: "memory");
        BAR;                               // ALL waves' stage(t) landed; iter t-1 reads consumed
        __builtin_amdgcn_sched_barrier(0); // pin: no hoist of reads above the barrier
        int s = t + 2; if (s >= KT) s = 0; // wrap re-stage: buffer never read
        stage(s, sb);                      // writes buf (t-1)%3 — safe post-barrier
        const char* base = Sbuf + cb * BUFB;
        bf16x8 af[MF], bfr[4];
        #pragma unroll
        for (int m = 0; m < MF; ++m) af[m] = *(const bf16x8*)(base + offA[m]);
        #pragma unroll
        for (int n = 0; n < 4; ++n) bfr[n] = *(const bf16x8*)(base + offB[n]);
        __builtin_amdgcn_s_setprio(1);
        #pragma unroll
        for (int m = 0; m < MF; ++m)
            #pragma unroll
            for (int n = 0; n < 4; ++n)
                acc[m][n] = __builtin_amdgcn_mfma_f32_16x16x32_bf16(af[m], bfr[n], acc[m][n], 0, 0, 0);
        __builtin_amdgcn_s_setprio(0);
        cb = (cb == 2) ? 0 : cb + 1;
        sb = (sb == 2) ? 0 : sb + 1;
    }

    int rbase = bm + wr * (MF * 16);
    int cbase = bn + wc * 64;
    #pragma unroll
    for (int n = 0; n < 4; ++n) {
        int col = cbase + n * 16 + lr;
        if (col >= N) continue;
        float bv = bias ? bias[col] : 0.0f;
        #pragma unroll
        for (int m = 0; m < MF; ++m) {
            #pragma unroll
            for (int rr = 0; rr < 4; ++rr) {
                int row = rbase + m * 16 + (l >> 4) * 4 + rr;
                if (row >= M) continue;
                float c = acc[m][n][rr] + bv;
                if (GELU) c = gelu_exact(c);
                if (GG > 0) c *= aux[row * 4 + col / (GG > 0 ? GG : 1)];
                if (resid) c += resid[(size_t)row * ldc + col];
                if (BF16OUT) ((unsigned short*)Cout)[(size_t)row * ldc + col] = f2bf(c);
                else ((float*)Cout)[(size_t)row * ldc + col] = c;
            }
        }
    }
}

// ---------- flash attention: one block per (b*h, 64-row q tile) ----------
__global__ __launch_bounds__(256) void k_attn(const unsigned short* __restrict__ qkv,
                                              unsigned short* __restrict__ ctx) {
    int bh = blockIdx.x;
    int qt = blockIdx.y;
    int b = bh >> 4, h = bh & 15;
    int tid = threadIdx.x;
    int l = tid & 63;
    int w = tid >> 6;
    int lr = l & 15;
    int lk = (l >> 4) * 8;

    __shared__ unsigned short Qs[64][72];
    __shared__ unsigned short Ks[64][72];
    __shared__ unsigned short Vt[64][72];
    __shared__ unsigned short Ps[64][72];

    const size_t base = (size_t)b * NSEQ * NQKV + (size_t)h * 64;
    int q0 = qt * 64;

    {
        int row = tid >> 2, ds = (tid & 3) * 16;
        int qrow = q0 + row;
        if (qrow < NSEQ) {
            const unsigned short* src = qkv + base + (size_t)qrow * NQKV + ds;
            #pragma unroll
            for (int j = 0; j < 16; ++j) Qs[row][ds + j] = f2bf(bf2f(src[j]) * 0.125f);
        } else {
            #pragma unroll
            for (int j = 0; j < 16; ++j) Qs[row][ds + j] = 0;
        }
    }

    float m_run[4], l_run[4];
    f32x4 o[4];
    #pragma unroll
    for (int r = 0; r < 4; ++r) { m_run[r] = -1e30f; l_run[r] = 0.0f; }
    #pragma unroll
    for (int n = 0; n < 4; ++n) o[n] = (f32x4){0.f, 0.f, 0.f, 0.f};

    for (int kt = 0; kt < 10; ++kt) {
        __syncthreads();
        {
            int row = tid >> 2, ds = (tid & 3) * 16;
            int key = kt * 64 + row;
            if (key < NSEQ) {
                const unsigned short* ksrc = qkv + base + (size_t)key * NQKV + 1024 + ds;
                *(ushort8*)&Ks[row][ds] = *(const ushort8*)ksrc;
                *(ushort8*)&Ks[row][ds + 8] = *(const ushort8*)(ksrc + 8);
                const unsigned short* vsrc = qkv + base + (size_t)key * NQKV + 2048 + ds;
                #pragma unroll
                for (int j = 0; j < 16; ++j) Vt[ds + j][row] = vsrc[j];
            } else {
                ushort8 z = {};
                *(ushort8*)&Ks[row][ds] = z;
                *(ushort8*)&Ks[row][ds + 8] = z;
                #pragma unroll
                for (int j = 0; j < 16; ++j) Vt[ds + j][row] = 0;
            }
        }
        __syncthreads();

        f32x4 s[4];
        #pragma unroll
        for (int n = 0; n < 4; ++n) s[n] = (f32x4){0.f, 0.f, 0.f, 0.f};
        #pragma unroll
        for (int ks = 0; ks < 2; ++ks) {
            bf16x8 qa = *(const bf16x8*)&Qs[w * 16 + lr][ks * 32 + lk];
            #pragma unroll
            for (int n = 0; n < 4; ++n) {
                bf16x8 kb = *(const bf16x8*)&Ks[n * 16 + lr][ks * 32 + lk];
                s[n] = __builtin_amdgcn_mfma_f32_16x16x32_bf16(qa, kb, s[n], 0, 0, 0);
            }
        }
        #pragma unroll
        for (int n = 0; n < 4; ++n) {
            int col = kt * 64 + n * 16 + lr;
            if (col >= NSEQ) {
                #pragma unroll
                for (int r = 0; r < 4; ++r) s[n][r] = -1e30f;
            }
        }
        float tmax[4];
        #pragma unroll
        for (int r = 0; r < 4; ++r)
            tmax[r] = fmaxf(fmaxf(s[0][r], s[1][r]), fmaxf(s[2][r], s[3][r]));
        #pragma unroll
        for (int off = 1; off < 16; off <<= 1) {
            #pragma unroll
            for (int r = 0; r < 4; ++r) tmax[r] = fmaxf(tmax[r], __shfl_xor(tmax[r], off));
        }
        float alpha[4], rs[4];
        #pragma unroll
        for (int r = 0; r < 4; ++r) {
            float mn = fmaxf(m_run[r], tmax[r]);
            alpha[r] = __expf(m_run[r] - mn);
            m_run[r] = mn;
            rs[r] = 0.0f;
        }
        #pragma unroll
        for (int n = 0; n < 4; ++n) {
            #pragma unroll
            for (int r = 0; r < 4; ++r) {
                float p = __expf(s[n][r] - m_run[r]);
                s[n][r] = p;
                rs[r] += p;
            }
        }
        #pragma unroll
        for (int off = 1; off < 16; off <<= 1) {
            #pragma unroll
            for (int r = 0; r < 4; ++r) rs[r] += __shfl_xor(rs[r], off);
        }
        #pragma unroll
        for (int r = 0; r < 4; ++r) l_run[r] = l_run[r] * alpha[r] + rs[r];
        #pragma unroll
        for (int n = 0; n < 4; ++n) {
            #pragma unroll
            for (int r = 0; r < 4; ++r) o[n][r] *= alpha[r];
        }
        #pragma unroll
        for (int n = 0; n < 4; ++n) {
            #pragma unroll
            for (int r = 0; r < 4; ++r)
                Ps[w * 16 + (l >> 4) * 4 + r][n * 16 + lr] = f2bf(s[n][r]);
        }
        __syncthreads();
        #pragma unroll
        for (int ks = 0; ks < 2; ++ks) {
            bf16x8 pa = *(const bf16x8*)&Ps[w * 16 + lr][ks * 32 + lk];
            #pragma unroll
            for (int n = 0; n < 4; ++n) {
                bf16x8 vb = *(const bf16x8*)&Vt[n * 16 + lr][ks * 32 + lk];
                o[n] = __builtin_amdgcn_mfma_f32_16x16x32_bf16(pa, vb, o[n], 0, 0, 0);
            }
        }
    }
    #pragma unroll
    for (int r = 0; r < 4; ++r) {
        int qrow = q0 + w * 16 + (l >> 4) * 4 + r;
        if (qrow < NSEQ) {
            float inv = (l_run[r] > 0.f) ? 1.0f / l_run[r] : 0.0f;
            #pragma unroll
            for (int n = 0; n < 4; ++n)
                ctx[((size_t)b * NSEQ + qrow) * EMB + h * 64 + n * 16 + lr] = f2bf(o[n][r] * inv);
        }
    }
}

extern "C" void kernel_launch(void* const* d_in, const int* in_sizes, int n_in,
                              void* d_out, int out_size, void* d_ws, size_t ws_size,
                              hipStream_t stream) {
    const float* tokens      = (const float*)d_in[0];
    const float* ln1_g       = (const float*)d_in[1];
    const float* ln1_b       = (const float*)d_in[2];
    const float* qkv_w       = (const float*)d_in[3];
    const float* qkv_b       = (const float*)d_in[4];
    const float* proj_w      = (const float*)d_in[5];
    const float* proj_b      = (const float*)d_in[6];
    const float* lora_gate_w = (const float*)d_in[7];
    const float* lora_A      = (const float*)d_in[8];
    const float* lora_B      = (const float*)d_in[9];
    const float* ln2_g       = (const float*)d_in[10];
    const float* ln2_b       = (const float*)d_in[11];
    const float* fc1_w       = (const float*)d_in[12];
    const float* fc1_b       = (const float*)d_in[13];
    const float* fc2_w       = (const float*)d_in[14];
    const float* fc2_b       = (const float*)d_in[15];
    const float* ad_gate_w   = (const float*)d_in[16];
    const float* ad_down_w   = (const float*)d_in[17];
    const float* ad_down_b   = (const float*)d_in[18];
    const float* ad_up_w     = (const float*)d_in[19];
    const float* ad_up_b     = (const float*)d_in[20];

    char* ws = (char*)d_ws;
    size_t off = 0;
    auto alloc = [&](size_t bytes) -> void* {
        void* p = ws + off;
        off += (bytes + 255) & ~(size_t)255;
        return p;
    };

    unsigned short* w_qkv  = (unsigned short*)alloc((size_t)NQKV * EMB * 2);
    unsigned short* w_proj = (unsigned short*)alloc((size_t)EMB * EMB * 2);
    unsigned short* w_fc1  = (unsigned short*)alloc((size_t)FFD * EMB * 2);
    unsigned short* w_fc2  = (unsigned short*)alloc((size_t)EMB * FFD * 2);
    unsigned short* w_acat = (unsigned short*)alloc((size_t)64 * EMB * 2);
    unsigned short* w_bcat = (unsigned short*)alloc((size_t)NQKV * 64 * 2);
    unsigned short* w_dcat = (unsigned short*)alloc((size_t)256 * EMB * 2);
    unsigned short* w_u    = (unsigned short*)alloc((size_t)EMB * 256 * 2);

    unsigned short* u1 = (unsigned short*)alloc((size_t)TOK * EMB * 2);  // normed -> mlpin
    unsigned short* u2 = (unsigned short*)alloc((size_t)TOK * EMB * 2);  // ctx
    unsigned short* u3 = (unsigned short*)alloc((size_t)TOK * FFD * 2);  // qkv -> h1
    float* tok2  = (float*)alloc((size_t)TOK * EMB * 4);
    unsigned short* hw  = (unsigned short*)alloc((size_t)TOK * 64 * 2);
    unsigned short* ahw = (unsigned short*)alloc((size_t)TOK * 256 * 2);
    float* gates = (float*)alloc((size_t)TOK * 4 * 4);
    float* ag    = (float*)alloc((size_t)TOK * 4 * 4);

    unsigned short* normed = u1;
    unsigned short* mlpin  = u1;
    unsigned short* ctx    = u2;
    unsigned short* qkv    = u3;
    unsigned short* h1     = u3;

    // ---- weight conversion / packing (3 dispatches) ----
    k_pack_all<<<2048, 256, 0, stream>>>(qkv_w, proj_w, fc1_w, fc2_w, lora_A, ad_down_w,
                                         w_qkv, w_proj, w_fc1, w_fc2, w_acat, w_dcat);
    k_pack_bcat<<<(NQKV * 64 + 255) / 256, 256, 0, stream>>>(lora_B, w_bcat);
    k_pack_u<<<(EMB * 256 + 255) / 256, 256, 0, stream>>>(ad_up_w, w_u);

    // ---- forward ----
    k_ln_gates<<<TOK, 256, 0, stream>>>(tokens, ln1_g, ln1_b, lora_gate_w, normed, gates);
    // lora down: hw = gates * (normed @ lora_A^T), bf16 out, gate group 16  (MF=2: 145 blocks)
    k_gemm<false, true, 16, 2><<<145, 256, 0, stream>>>(
        normed, EMB, w_acat, EMB, EMB, TOK, 64,
        nullptr, nullptr, 0, nullptr, nullptr, gates, hw, 64, 1);
    // qkv = normed @ qkv_w^T + hw @ bcat^T + qkv_b  (MF=4)
    k_gemm<false, true, 0, 4><<<73 * 24, 256, 0, stream>>>(
        normed, EMB, w_qkv, EMB, EMB, TOK, NQKV,
        hw, w_bcat, 64, qkv_b, nullptr, nullptr, qkv, NQKV, 24);
    k_attn<<<dim3(256, 10), 256, 0, stream>>>(qkv, ctx);
    // tok2 = tokens + ctx @ proj^T + proj_b   (fp32, MF=2: 1160 blocks)
    k_gemm<false, false, 0, 2><<<145 * 8, 256, 0, stream>>>(
        ctx, EMB, w_proj, EMB, EMB, TOK, EMB,
        nullptr, nullptr, 0, proj_b, tokens, nullptr, tok2, EMB, 8);
    k_ln_gates<<<TOK, 256, 0, stream>>>(tok2, ln2_g, ln2_b, ad_gate_w, mlpin, ag);
    // adapter down: ahw = ag * gelu(mlpin @ d^T + db), bf16, gate group 64 (MF=2: 290 blocks)
    k_gemm<true, true, 64, 2><<<145 * 2, 256, 0, stream>>>(
        mlpin, EMB, w_dcat, EMB, EMB, TOK, 256,
        nullptr, nullptr, 0, ad_down_b, nullptr, ag, ahw, 256, 2);
    // d_out = tok2 + fc2_b + ag @ ad_up_b
    k_fc2init<<<TOK, 256, 0, stream>>>(tok2, fc2_b, ag, ad_up_b, (float*)d_out);
    // h1 = gelu(mlpin @ fc1^T + fc1_b)  (MF=4)
    k_gemm<true, true, 0, 4><<<73 * 32, 256, 0, stream>>>(
        mlpin, EMB, w_fc1, EMB, EMB, TOK, FFD,
        nullptr, nullptr, 0, fc1_b, nullptr, nullptr, h1, FFD, 32);
    // d_out = prepped + h1 @ fc2^T + ahw @ u^T  (MF=2: 1160 blocks; resid aliases Cout,
    // each elem read-then-written by the same thread)
    k_gemm<false, false, 0, 2><<<145 * 8, 256, 0, stream>>>(
        h1, FFD, w_fc2, FFD, FFD, TOK, EMB,
        ahw, w_u, 256, nullptr, (const float*)d_out, nullptr, (float*)d_out, EMB, 8);
}